// Round 2
// baseline (679.084 us; speedup 1.0000x reference)
//
#include <hip/hip_runtime.h>

typedef unsigned short u16;
typedef __attribute__((ext_vector_type(4))) float f32x4;
typedef __attribute__((ext_vector_type(8))) short s16x8;
typedef __attribute__((ext_vector_type(4))) u16   u16x4;
typedef __attribute__((ext_vector_type(8))) u16   u16x8;

#define DEV static __device__ __forceinline__

constexpr int Ll = 4096;

DEV float bf2f(u16 v) { unsigned u = ((unsigned)v) << 16; float f; __builtin_memcpy(&f, &u, 4); return f; }
DEV u16 f2bf(float f) { // round-to-nearest-even
    unsigned u; __builtin_memcpy(&u, &f, 4);
    u += 0x7fffu + ((u >> 16) & 1u);
    return (u16)(u >> 16);
}
// fast truncation split (for GEMM staging; hi+lo ~ 24-bit accurate)
DEV void tsplit(float v, u16& h, u16& l) {
    unsigned ui; __builtin_memcpy(&ui, &v, 4);
    h = (u16)(ui >> 16);
    unsigned um = ui & 0xffff0000u; float hf; __builtin_memcpy(&hf, &um, 4);
    float lf = v - hf; unsigned ul; __builtin_memcpy(&ul, &lf, 4);
    l = (u16)(ul >> 16);
}

DEV f32x4 mfma16(s16x8 a, s16x8 b, f32x4 c) {
    return __builtin_amdgcn_mfma_f32_16x16x32_bf16(a, b, c, 0, 0, 0);
}

// ---------------- converts ----------------
__global__ __launch_bounds__(256) void k_split(const float* __restrict__ s,
                                               u16* __restrict__ hi, u16* __restrict__ lo) {
    size_t i = ((size_t)blockIdx.x * 256 + threadIdx.x) * 4;
    f32x4 v = *(const f32x4*)(s + i);
    u16x4 h, l;
#pragma unroll
    for (int j = 0; j < 4; j++) {
        u16 hh = f2bf(v[j]);
        h[j] = hh;
        l[j] = f2bf(v[j] - bf2f(hh));
    }
    *(u16x4*)(hi + i) = h;
    *(u16x4*)(lo + i) = l;
}

__global__ __launch_bounds__(256) void k_conv(const float* __restrict__ s, u16* __restrict__ d) {
    size_t i = ((size_t)blockIdx.x * 256 + threadIdx.x) * 4;
    f32x4 v = *(const f32x4*)(s + i);
    u16x4 h;
#pragma unroll
    for (int j = 0; j < 4; j++) h[j] = f2bf(v[j]);
    *(u16x4*)(d + i) = h;
}

// wt[m*64+d] = omega[d*256+m] * DH^-0.25, split hi/lo
__global__ __launch_bounds__(256) void k_omega(const float* __restrict__ om,
                                               u16* __restrict__ wh, u16* __restrict__ wl) {
    int i = blockIdx.x * 256 + threadIdx.x; // 16384
    int m = i >> 6, d = i & 63;
    float v = om[d * 256 + m] * 0.35355339059327373f;
    u16 h = f2bf(v);
    wh[i] = h;
    wl[i] = f2bf(v - bf2f(h));
}

__global__ __launch_bounds__(256) void k_zero(float* __restrict__ p, int n) {
    int i = (blockIdx.x * 256 + threadIdx.x) * 4;
    if (i < n) { f32x4 z; z[0]=0.f; z[1]=0.f; z[2]=0.f; z[3]=0.f; *(f32x4*)(p + i) = z; }
}

// ---------------- QKV GEMM: [16384x1024](f32, inline-split) x [3072x1024]^T (pre-split) ----------------
// 3-MFMA split product. Output: Q,K -> QK[row][2048] (hi; + lo if STORE_LO); V -> bf16.
template <bool STORE_LO>
__global__ __launch_bounds__(256) void k_gemm_qkv(
    const float* __restrict__ x,
    const u16* __restrict__ Bh, const u16* __restrict__ Bl,
    u16* __restrict__ QKh, u16* __restrict__ QKl, u16* __restrict__ Vb) {
    __shared__ __align__(16) u16 sm[4 * 128 * 40]; // 40960 B
    u16* sAh = sm;
    u16* sAl = sm + 128 * 40;
    u16* sBh = sm + 2 * 128 * 40;
    u16* sBl = sm + 3 * 128 * 40;
    const int tid = threadIdx.x, wave = tid >> 6, lane = tid & 63;
    const int lr = lane & 15, lk = (lane >> 4) * 8;
    const int m0 = blockIdx.y * 128, n0 = blockIdx.x * 128;
    const int wm = (wave >> 1) * 64, wn = (wave & 1) * 64;
    const int srow = tid >> 1, sc = (tid & 1) * 16;

    f32x4 acc[4][4];
#pragma unroll
    for (int i = 0; i < 4; i++)
#pragma unroll
        for (int j = 0; j < 4; j++)
#pragma unroll
            for (int r = 0; r < 4; r++) acc[i][j][r] = 0.f;

    const size_t gA = (size_t)(m0 + srow) * 1024 + sc;
    const size_t gB = (size_t)(n0 + srow) * 1024 + sc;

    for (int k0 = 0; k0 < 1024; k0 += 32) {
        { // A: load f32 x, split inline
            const float* xp = x + gA + k0;
            u16x8 h0, h1, l0v, l1v;
#pragma unroll
            for (int p = 0; p < 2; p++) {
                f32x4 v0 = *(const f32x4*)(xp + p * 8);
                f32x4 v1 = *(const f32x4*)(xp + p * 8 + 4);
#pragma unroll
                for (int j = 0; j < 4; j++) {
                    u16 hh, ll;
                    tsplit(v0[j], hh, ll);
                    if (p == 0) { h0[j] = hh; l0v[j] = ll; } else { h1[j] = hh; l1v[j] = ll; }
                    tsplit(v1[j], hh, ll);
                    if (p == 0) { h0[4 + j] = hh; l0v[4 + j] = ll; } else { h1[4 + j] = hh; l1v[4 + j] = ll; }
                }
            }
            *(u16x8*)&sAh[srow * 40 + sc]     = h0;
            *(u16x8*)&sAh[srow * 40 + sc + 8] = h1;
            *(u16x8*)&sAl[srow * 40 + sc]     = l0v;
            *(u16x8*)&sAl[srow * 40 + sc + 8] = l1v;
        }
        *(u16x8*)&sBh[srow * 40 + sc]     = *(const u16x8*)(Bh + gB + k0);
        *(u16x8*)&sBh[srow * 40 + sc + 8] = *(const u16x8*)(Bh + gB + k0 + 8);
        *(u16x8*)&sBl[srow * 40 + sc]     = *(const u16x8*)(Bl + gB + k0);
        *(u16x8*)&sBl[srow * 40 + sc + 8] = *(const u16x8*)(Bl + gB + k0 + 8);
        __syncthreads();
        s16x8 ah[4], al[4], bh2[4], bl2[4];
#pragma unroll
        for (int f = 0; f < 4; f++) {
            ah[f]  = *(const s16x8*)&sAh[(wm + f * 16 + lr) * 40 + lk];
            al[f]  = *(const s16x8*)&sAl[(wm + f * 16 + lr) * 40 + lk];
            bh2[f] = *(const s16x8*)&sBh[(wn + f * 16 + lr) * 40 + lk];
            bl2[f] = *(const s16x8*)&sBl[(wn + f * 16 + lr) * 40 + lk];
        }
#pragma unroll
        for (int i = 0; i < 4; i++)
#pragma unroll
            for (int j = 0; j < 4; j++) {
                acc[i][j] = mfma16(ah[i], bh2[j], acc[i][j]);
                acc[i][j] = mfma16(ah[i], bl2[j], acc[i][j]);
                acc[i][j] = mfma16(al[i], bh2[j], acc[i][j]);
            }
        __syncthreads();
    }

    // epilogue: restage 32-row groups through LDS for coalesced stores
    float* ep = (float*)sm; // [32][132]
    const int sec = n0 >> 10; // 0 -> Q ; 1 -> K ; 2 -> V
    for (int g = 0; g < 4; g++) {
        __syncthreads();
        if ((wave >> 1) == (g >> 1)) {
#pragma unroll
            for (int fi = 0; fi < 2; fi++) {
                int fm = (g & 1) * 2 + fi;
#pragma unroll
                for (int j = 0; j < 4; j++)
#pragma unroll
                    for (int r = 0; r < 4; r++)
                        ep[(fi * 16 + (lane >> 4) * 4 + r) * 132 + wn + j * 16 + lr] = acc[fm][j][r];
            }
        }
        __syncthreads();
        int row = tid >> 3, c0 = (tid & 7) * 16;
        int grow = m0 + g * 32 + row;
        float v[16];
#pragma unroll
        for (int j = 0; j < 16; j++) v[j] = ep[row * 132 + c0 + j];
        if (sec < 2) {
            u16x8 h0, h1;
#pragma unroll
            for (int j = 0; j < 8; j++) { h0[j] = f2bf(v[j]); h1[j] = f2bf(v[8 + j]); }
            size_t o = (size_t)grow * 2048 + (n0 + c0);
            *(u16x8*)(QKh + o) = h0; *(u16x8*)(QKh + o + 8) = h1;
            if (STORE_LO) {
                u16x8 q0, q1;
#pragma unroll
                for (int j = 0; j < 8; j++) {
                    q0[j] = f2bf(v[j] - bf2f(h0[j]));
                    q1[j] = f2bf(v[8 + j] - bf2f(h1[j]));
                }
                *(u16x8*)(QKl + o) = q0; *(u16x8*)(QKl + o + 8) = q1;
            }
        } else {
            u16x8 h0, h1;
#pragma unroll
            for (int j = 0; j < 8; j++) { h0[j] = f2bf(v[j]); h1[j] = f2bf(v[8 + j]); }
            size_t o = (size_t)grow * 1024 + (n0 - 2048 + c0);
            *(u16x8*)(Vb + o) = h0; *(u16x8*)(Vb + o + 8) = h1;
        }
    }
}

// ---------------- fused phi(K) + KV + Ksum ----------------
// grid (8 l-chunks of 512, 64 bh). NM=3: split-K 3-mfma phi; NM=2: hi-only K, split omega.
template <int NM>
__global__ __launch_bounds__(256) void k_phik_kv(
    const u16* __restrict__ QKh, const u16* __restrict__ QKl,
    const u16* __restrict__ wth, const u16* __restrict__ wtl,
    const u16* __restrict__ Vb, float* __restrict__ KVacc, float* __restrict__ Ksum) {
    __shared__ __align__(16) u16 sKh[64 * 72];
    __shared__ __align__(16) u16 sKl[64 * 72];
    __shared__ __align__(16) u16 sVt[64 * 72];
    __shared__ __align__(16) u16 sKfT[256 * 72];
    __shared__ float snsq[64];
    const int tid = threadIdx.x, wave = tid >> 6, lane = tid & 63;
    const int lr = lane & 15, lk = (lane >> 4) * 8;
    const int kc = blockIdx.x, bh = blockIdx.y;
    const int b = bh >> 4, h = bh & 15;

    s16x8 wbh[4][2], wbl[4][2];
#pragma unroll
    for (int fn = 0; fn < 4; fn++)
#pragma unroll
        for (int ks = 0; ks < 2; ks++) {
            size_t g = (size_t)(wave * 64 + fn * 16 + lr) * 64 + ks * 32 + lk;
            wbh[fn][ks] = *(const s16x8*)(wth + g);
            wbl[fn][ks] = *(const s16x8*)(wtl + g);
        }

    f32x4 akv[4][4];
#pragma unroll
    for (int i = 0; i < 4; i++)
#pragma unroll
        for (int j = 0; j < 4; j++)
#pragma unroll
            for (int r = 0; r < 4; r++) akv[i][j][r] = 0.f;
    float ksm[4] = {0.f, 0.f, 0.f, 0.f};

    for (int it = 0; it < 8; it++) {
        int l0 = kc * 512 + it * 64;
        __syncthreads();
        { // stage K (hi/lo) + nsq
            int row = tid >> 2, c0 = (tid & 3) * 16;
            size_t g = ((size_t)(b * Ll + l0 + row)) * 2048 + 1024 + h * 64 + c0;
            u16x8 h0 = *(const u16x8*)(QKh + g);
            u16x8 h1 = *(const u16x8*)(QKh + g + 8);
            *(u16x8*)&sKh[row * 72 + c0]     = h0;
            *(u16x8*)&sKh[row * 72 + c0 + 8] = h1;
            float s = 0.f;
            if (NM == 3) {
                u16x8 q0 = *(const u16x8*)(QKl + g);
                u16x8 q1 = *(const u16x8*)(QKl + g + 8);
                *(u16x8*)&sKl[row * 72 + c0]     = q0;
                *(u16x8*)&sKl[row * 72 + c0 + 8] = q1;
#pragma unroll
                for (int j = 0; j < 8; j++) {
                    float a = bf2f(h0[j]) + bf2f(q0[j]); s += a * a;
                    float c = bf2f(h1[j]) + bf2f(q1[j]); s += c * c;
                }
            } else {
#pragma unroll
                for (int j = 0; j < 8; j++) {
                    float a = bf2f(h0[j]); s += a * a;
                    float c = bf2f(h1[j]); s += c * c;
                }
            }
            s += __shfl_xor(s, 1); s += __shfl_xor(s, 2);
            if ((tid & 3) == 0) snsq[row] = s * 0.0625f;
        }
        { // stage V transposed
            int l = tid >> 2, d0 = (tid & 3) * 16;
            size_t g = ((size_t)(b * Ll + l0 + l)) * 1024 + h * 64 + d0;
            u16x8 v0 = *(const u16x8*)(Vb + g);
            u16x8 v1 = *(const u16x8*)(Vb + g + 8);
#pragma unroll
            for (int j = 0; j < 8; j++) {
                sVt[(d0 + j) * 72 + l] = v0[j];
                sVt[(d0 + 8 + j) * 72 + l] = v1[j];
            }
        }
        __syncthreads();
        // phi per fm, exp, transpose-store into sKfT (same-wave m rows), ksum in regs
#pragma unroll
        for (int fm = 0; fm < 4; fm++) {
            f32x4 ap[4];
#pragma unroll
            for (int fn = 0; fn < 4; fn++)
#pragma unroll
                for (int r = 0; r < 4; r++) ap[fn][r] = 0.f;
#pragma unroll
            for (int ks = 0; ks < 2; ks++) {
                s16x8 aH = *(const s16x8*)&sKh[(fm * 16 + lr) * 72 + ks * 32 + lk];
                s16x8 aL;
                if (NM == 3) aL = *(const s16x8*)&sKl[(fm * 16 + lr) * 72 + ks * 32 + lk];
#pragma unroll
                for (int fn = 0; fn < 4; fn++) {
                    ap[fn] = mfma16(aH, wbh[fn][ks], ap[fn]);
                    ap[fn] = mfma16(aH, wbl[fn][ks], ap[fn]);
                    if (NM == 3) ap[fn] = mfma16(aL, wbh[fn][ks], ap[fn]);
                }
            }
#pragma unroll
            for (int fn = 0; fn < 4; fn++) {
                u16x4 pk;
#pragma unroll
                for (int r = 0; r < 4; r++) {
                    float ns = snsq[fm * 16 + (lane >> 4) * 4 + r];
                    float val = __expf(ap[fn][r] - ns) * 0.0625f;
                    ksm[fn] += val;
                    pk[r] = f2bf(val);
                }
                *(u16x4*)&sKfT[(wave * 64 + fn * 16 + lr) * 72 + fm * 16 + (lane >> 4) * 4] = pk;
            }
        }
        // KV mfma (A: own-wave sKfT rows; B: sVt from barrier'd stage)
#pragma unroll
        for (int ks = 0; ks < 2; ks++) {
            s16x8 a4[4], b4[4];
#pragma unroll
            for (int f = 0; f < 4; f++) {
                a4[f] = *(const s16x8*)&sKfT[(wave * 64 + f * 16 + lr) * 72 + ks * 32 + lk];
                b4[f] = *(const s16x8*)&sVt[(f * 16 + lr) * 72 + ks * 32 + lk];
            }
#pragma unroll
            for (int fm = 0; fm < 4; fm++)
#pragma unroll
                for (int fn = 0; fn < 4; fn++)
                    akv[fm][fn] = mfma16(a4[fm], b4[fn], akv[fm][fn]);
        }
    }
#pragma unroll
    for (int fm = 0; fm < 4; fm++)
#pragma unroll
        for (int fn = 0; fn < 4; fn++)
#pragma unroll
            for (int r = 0; r < 4; r++) {
                int m = wave * 64 + fm * 16 + (lane >> 4) * 4 + r;
                int d = fn * 16 + lr;
                atomicAdd(&KVacc[((size_t)bh << 14) + m * 64 + d], akv[fm][fn][r]);
            }
    // ksum: reduce over the 4 lane-groups holding the same m
#pragma unroll
    for (int fn = 0; fn < 4; fn++) {
        ksm[fn] += __shfl_xor(ksm[fn], 16);
        ksm[fn] += __shfl_xor(ksm[fn], 32);
    }
    if (lane < 16) {
#pragma unroll
        for (int fn = 0; fn < 4; fn++)
            atomicAdd(&Ksum[bh * 256 + wave * 64 + fn * 16 + lane], ksm[fn]);
    }
}

// KVt[bh][d][m] = bf16(KVacc[bh][m][d])
__global__ __launch_bounds__(256) void k_kvt(const float* __restrict__ KVacc, u16* __restrict__ KVt) {
    int i = blockIdx.x * 256 + threadIdx.x;
    int bh = i >> 14, dd = (i >> 8) & 63, m = i & 255;
    KVt[i] = f2bf(KVacc[((size_t)bh << 14) + m * 64 + dd]);
}

// ---------------- fused phi(Q) + norm + attn ----------------
// grid (32, 64): block = 512 threads, 2 l-subtiles of 64.
template <int NM>
__global__ __launch_bounds__(512) void k_phiq_attn(
    const u16* __restrict__ QKh, const u16* __restrict__ QKl,
    const u16* __restrict__ wth, const u16* __restrict__ wtl,
    const u16* __restrict__ KVt, const float* __restrict__ Ksum,
    u16* __restrict__ attn) {
    __shared__ __align__(16) u16 sQh[64 * 72];
    __shared__ __align__(16) u16 sQl[64 * 72];
    __shared__ __align__(16) u16 sQf[64 * 264];
    __shared__ float sKs[256];
    __shared__ float snsq[64];
    __shared__ float snorm[64];
    const int tid = threadIdx.x, wave = tid >> 6, lane = tid & 63;
    const int lr = lane & 15, lk = (lane >> 4) * 8;
    const int bh = blockIdx.y, b = bh >> 4, h = bh & 15;
    const int mq = wave & 3;   // phi m-group
    const int lh = wave >> 2;  // phi l-half
    const int af = wave & 3;   // attn l-frag
    const int ad = wave >> 2;  // attn d-half

    // preload wt frags for this wave's m-range
    s16x8 wbh[4][2], wbl[4][2];
#pragma unroll
    for (int fn = 0; fn < 4; fn++)
#pragma unroll
        for (int ks = 0; ks < 2; ks++) {
            size_t g = (size_t)(mq * 64 + fn * 16 + lr) * 64 + ks * 32 + lk;
            wbh[fn][ks] = *(const s16x8*)(wth + g);
            wbl[fn][ks] = *(const s16x8*)(wtl + g);
        }
    // preload KV^T B-frags (d rows, m k-dim) for this wave's d-range
    s16x8 kvb[2][8];
#pragma unroll
    for (int fn = 0; fn < 2; fn++)
#pragma unroll
        for (int ks = 0; ks < 8; ks++)
            kvb[fn][ks] = *(const s16x8*)(KVt + ((size_t)bh << 14) +
                                          (size_t)(ad * 32 + fn * 16 + lr) * 256 + ks * 32 + lk);
    if (tid < 256) sKs[tid] = Ksum[bh * 256 + tid];

    for (int st = 0; st < 2; st++) {
        const int l0 = (blockIdx.x * 2 + st) * 64;
        __syncthreads();
        { // stage Q hi/lo + nsq
            int row = tid >> 3, c0 = (tid & 7) * 8;
            size_t g = ((size_t)(b * Ll + l0 + row)) * 2048 + h * 64 + c0;
            u16x8 vh = *(const u16x8*)(QKh + g);
            *(u16x8*)&sQh[row * 72 + c0] = vh;
            float s = 0.f;
            if (NM == 3) {
                u16x8 vl = *(const u16x8*)(QKl + g);
                *(u16x8*)&sQl[row * 72 + c0] = vl;
#pragma unroll
                for (int j = 0; j < 8; j++) { float a = bf2f(vh[j]) + bf2f(vl[j]); s += a * a; }
            } else {
#pragma unroll
                for (int j = 0; j < 8; j++) { float a = bf2f(vh[j]); s += a * a; }
            }
            s += __shfl_xor(s, 1); s += __shfl_xor(s, 2); s += __shfl_xor(s, 4);
            if ((tid & 7) == 0) snsq[row] = s * 0.0625f;
        }
        __syncthreads();
        // phi -> sQf[l][m]
#pragma unroll
        for (int fm = 0; fm < 2; fm++) {
            f32x4 ap[4];
#pragma unroll
            for (int fn = 0; fn < 4; fn++)
#pragma unroll
                for (int r = 0; r < 4; r++) ap[fn][r] = 0.f;
#pragma unroll
            for (int ks = 0; ks < 2; ks++) {
                s16x8 aH = *(const s16x8*)&sQh[(lh * 32 + fm * 16 + lr) * 72 + ks * 32 + lk];
                s16x8 aL;
                if (NM == 3) aL = *(const s16x8*)&sQl[(lh * 32 + fm * 16 + lr) * 72 + ks * 32 + lk];
#pragma unroll
                for (int fn = 0; fn < 4; fn++) {
                    ap[fn] = mfma16(aH, wbh[fn][ks], ap[fn]);
                    ap[fn] = mfma16(aH, wbl[fn][ks], ap[fn]);
                    if (NM == 3) ap[fn] = mfma16(aL, wbh[fn][ks], ap[fn]);
                }
            }
#pragma unroll
            for (int fn = 0; fn < 4; fn++)
#pragma unroll
                for (int r = 0; r < 4; r++) {
                    int l = lh * 32 + fm * 16 + (lane >> 4) * 4 + r;
                    int m = mq * 64 + fn * 16 + lr;
                    sQf[l * 264 + m] = f2bf(__expf(ap[fn][r] - snsq[l]) * 0.0625f);
                }
        }
        __syncthreads();
        // norm[l] = sum_m Qf * Ksum
        {
            int l = tid >> 3, m0 = (tid & 7) * 32;
            float s = 0.f;
#pragma unroll
            for (int j = 0; j < 32; j++) s += bf2f(sQf[l * 264 + m0 + j]) * sKs[m0 + j];
            s += __shfl_xor(s, 1); s += __shfl_xor(s, 2); s += __shfl_xor(s, 4);
            if ((tid & 7) == 0) snorm[l] = s;
        }
        // attn mfma: C[l][d]
        f32x4 aa[2];
#pragma unroll
        for (int fn = 0; fn < 2; fn++)
#pragma unroll
            for (int r = 0; r < 4; r++) aa[fn][r] = 0.f;
#pragma unroll
        for (int ks = 0; ks < 8; ks++) {
            s16x8 a = *(const s16x8*)&sQf[(af * 16 + lr) * 264 + ks * 32 + lk];
            aa[0] = mfma16(a, kvb[0][ks], aa[0]);
            aa[1] = mfma16(a, kvb[1][ks], aa[1]);
        }
        __syncthreads();
        float* ep = (float*)sQf; // [64][68]
#pragma unroll
        for (int fn = 0; fn < 2; fn++)
#pragma unroll
            for (int r = 0; r < 4; r++) {
                int l = af * 16 + (lane >> 4) * 4 + r;
                int d = ad * 32 + fn * 16 + lr;
                ep[l * 68 + d] = aa[fn][r];
            }
        __syncthreads();
        {
            int l = tid >> 3, d0 = (tid & 7) * 8;
            float inv = 1.0f / fmaxf(snorm[l], 1e-6f);
            u16x8 o;
#pragma unroll
            for (int j = 0; j < 8; j++) o[j] = f2bf(ep[l * 68 + d0 + j] * inv);
            *(u16x8*)(attn + ((size_t)(b * Ll + l0 + l)) * 1024 + h * 64 + d0) = o;
        }
    }
}

// ---------------- final GEMM: attn @ Wo^T + bo -> f32 out ----------------
__global__ __launch_bounds__(256) void k_gemm_out(const u16* __restrict__ Ab, const u16* __restrict__ Bw,
                                                  const float* __restrict__ bias, float* __restrict__ outp) {
    __shared__ __align__(16) u16 sm[2 * 128 * 40];
    u16* sA = sm;
    u16* sB = sm + 128 * 40;
    const int tid = threadIdx.x, wave = tid >> 6, lane = tid & 63;
    const int lr = lane & 15, lk = (lane >> 4) * 8;
    const int m0 = blockIdx.y * 128, n0 = blockIdx.x * 128;
    const int wm = (wave >> 1) * 64, wn = (wave & 1) * 64;
    const int srow = tid >> 1, sc = (tid & 1) * 16;

    f32x4 acc[4][4];
#pragma unroll
    for (int i = 0; i < 4; i++)
#pragma unroll
        for (int j = 0; j < 4; j++)
#pragma unroll
            for (int r = 0; r < 4; r++) acc[i][j][r] = 0.f;

    const size_t gA = (size_t)(m0 + srow) * 1024 + sc;
    const size_t gB = (size_t)(n0 + srow) * 1024 + sc;
    for (int k0 = 0; k0 < 1024; k0 += 32) {
        *(u16x8*)&sA[srow * 40 + sc]     = *(const u16x8*)(Ab + gA + k0);
        *(u16x8*)&sA[srow * 40 + sc + 8] = *(const u16x8*)(Ab + gA + k0 + 8);
        *(u16x8*)&sB[srow * 40 + sc]     = *(const u16x8*)(Bw + gB + k0);
        *(u16x8*)&sB[srow * 40 + sc + 8] = *(const u16x8*)(Bw + gB + k0 + 8);
        __syncthreads();
        s16x8 a[4], bb[4];
#pragma unroll
        for (int f = 0; f < 4; f++) {
            a[f]  = *(const s16x8*)&sA[(wm + f * 16 + lr) * 40 + lk];
            bb[f] = *(const s16x8*)&sB[(wn + f * 16 + lr) * 40 + lk];
        }
#pragma unroll
        for (int i = 0; i < 4; i++)
#pragma unroll
            for (int j = 0; j < 4; j++)
                acc[i][j] = mfma16(a[i], bb[j], acc[i][j]);
        __syncthreads();
    }
    float* ep = (float*)sm; // [32][132]
    for (int g = 0; g < 4; g++) {
        __syncthreads();
        if ((wave >> 1) == (g >> 1)) {
#pragma unroll
            for (int fi = 0; fi < 2; fi++) {
                int fm = (g & 1) * 2 + fi;
#pragma unroll
                for (int j = 0; j < 4; j++)
#pragma unroll
                    for (int r = 0; r < 4; r++)
                        ep[(fi * 16 + (lane >> 4) * 4 + r) * 132 + wn + j * 16 + lr] = acc[fm][j][r];
            }
        }
        __syncthreads();
        int row = tid >> 3, c0 = (tid & 7) * 16;
        int grow = m0 + g * 32 + row;
        float vv[16];
#pragma unroll
        for (int j = 0; j < 16; j++) vv[j] = ep[row * 132 + c0 + j] + bias[n0 + c0 + j];
#pragma unroll
        for (int p = 0; p < 4; p++) {
            f32x4 t;
#pragma unroll
            for (int q = 0; q < 4; q++) t[q] = vv[p * 4 + q];
            *(f32x4*)(outp + (size_t)grow * 1024 + n0 + c0 + p * 4) = t;
        }
    }
}

extern "C" void kernel_launch(void* const* d_in, const int* in_sizes, int n_in,
                              void* d_out, int out_size, void* d_ws, size_t ws_size,
                              hipStream_t stream) {
    (void)in_sizes; (void)n_in; (void)out_size;
    const float* x  = (const float*)d_in[0];
    const float* Wq = (const float*)d_in[1];
    const float* Wk = (const float*)d_in[2];
    const float* Wv = (const float*)d_in[3];
    const float* Wo = (const float*)d_in[4];
    const float* bo = (const float*)d_in[5];
    const float* om = (const float*)d_in[6];

    // Path A (split Q/K storage) needs 188,874,752 B; Path B needs 121,765,888 B.
    const bool pa = ws_size >= (size_t)188874752;

    char* w = (char*)d_ws;
    size_t o = 0;
    auto take = [&](size_t n) { char* p = w + o; o += n; return p; };
    u16* QKh = (u16*)take(67108864);
    u16* QKl = pa ? (u16*)take(67108864) : QKh; // dummy alias in path B (never read)
    u16* Vb  = (u16*)take(33554432);
    u16* Wh  = (u16*)take(6291456);
    u16* Wl  = (u16*)take(6291456);
    u16* Wob = (u16*)take(2097152);
    u16* wth = (u16*)take(32768);
    u16* wtl = (u16*)take(32768);
    float* KVacc = (float*)take(4194304);
    float* Ksum  = (float*)take(65536);   // contiguous after KVacc for k_zero
    u16* KVt = (u16*)take(2097152);
    u16* attn = Vb; // alias: V dead after k_phik_kv

    k_split<<<1024, 256, 0, stream>>>(Wq, Wh, Wl);
    k_split<<<1024, 256, 0, stream>>>(Wk, Wh + 1048576, Wl + 1048576);
    k_split<<<1024, 256, 0, stream>>>(Wv, Wh + 2097152, Wl + 2097152);
    k_conv<<<1024, 256, 0, stream>>>(Wo, Wob);
    k_omega<<<64, 256, 0, stream>>>(om, wth, wtl);
    k_zero<<<1040, 256, 0, stream>>>(KVacc, 1064960); // KVacc + Ksum

    if (pa) k_gemm_qkv<true ><<<dim3(24, 128), 256, 0, stream>>>(x, Wh, Wl, QKh, QKl, Vb);
    else    k_gemm_qkv<false><<<dim3(24, 128), 256, 0, stream>>>(x, Wh, Wl, QKh, QKl, Vb);

    if (pa) k_phik_kv<3><<<dim3(8, 64), 256, 0, stream>>>(QKh, QKl, wth, wtl, Vb, KVacc, Ksum);
    else    k_phik_kv<2><<<dim3(8, 64), 256, 0, stream>>>(QKh, QKl, wth, wtl, Vb, KVacc, Ksum);

    k_kvt<<<4096, 256, 0, stream>>>(KVacc, KVt);

    if (pa) k_phiq_attn<3><<<dim3(32, 64), 512, 0, stream>>>(QKh, QKl, wth, wtl, KVt, Ksum, attn);
    else    k_phiq_attn<2><<<dim3(32, 64), 512, 0, stream>>>(QKh, QKl, wth, wtl, KVt, Ksum, attn);

    k_gemm_out<<<dim3(8, 128), 256, 0, stream>>>(attn, Wob, bo, (float*)d_out);
}

// Round 3
// 592.663 us; speedup vs baseline: 1.1458x; 1.1458x over previous
//
#include <hip/hip_runtime.h>

typedef unsigned short u16;
typedef __attribute__((ext_vector_type(4))) float f32x4;
typedef __attribute__((ext_vector_type(8))) short s16x8;
typedef __attribute__((ext_vector_type(4))) u16   u16x4;
typedef __attribute__((ext_vector_type(8))) u16   u16x8;

#define DEV static __device__ __forceinline__

constexpr int Ll = 4096;

DEV float bf2f(u16 v) { unsigned u = ((unsigned)v) << 16; float f; __builtin_memcpy(&f, &u, 4); return f; }
DEV u16 f2bf(float f) { // round-to-nearest-even
    unsigned u; __builtin_memcpy(&u, &f, 4);
    u += 0x7fffu + ((u >> 16) & 1u);
    return (u16)(u >> 16);
}

DEV f32x4 mfma16(s16x8 a, s16x8 b, f32x4 c) {
    return __builtin_amdgcn_mfma_f32_16x16x32_bf16(a, b, c, 0, 0, 0);
}

#if defined(__has_builtin)
#if __has_builtin(__builtin_amdgcn_global_load_lds)
#define HAS_GLLDS 1
#endif
#endif
#ifndef HAS_GLLDS
#define HAS_GLLDS 0
#endif

// Stage a [128][32] u16 tile (8KB) into DST with XOR-swizzle col^(((row>>1)&3)<<3).
// Global: SRC + (ROWBASE+row)*1024 + k0 + col. gload_lds path: linear LDS dest,
// inverse-swizzled global source (same involution). Fallback: reg-staged swizzled writes.
#if HAS_GLLDS
#define STAGE_T(DST, SRC, ROWBASE)                                                        \
  { _Pragma("unroll") for (int j_ = 0; j_ < 2; j_++) {                                    \
      int row_ = wave * 32 + j_ * 16 + (lane >> 2);                                       \
      int col_ = ((lane & 3) ^ ((row_ >> 1) & 3)) * 8;                                    \
      const u16* gp_ = (SRC) + (size_t)((ROWBASE) + row_) * 1024 + k0 + col_;             \
      __builtin_amdgcn_global_load_lds(                                                   \
          (const __attribute__((address_space(1))) unsigned int*)gp_,                     \
          (__attribute__((address_space(3))) unsigned int*)((DST) + (wave * 2 + j_) * 512), \
          16, 0, 0); } }
#else
#define STAGE_T(DST, SRC, ROWBASE)                                                        \
  { int row_ = tid >> 1, cb_ = (tid & 1) * 16;                                            \
    const u16* gp_ = (SRC) + (size_t)((ROWBASE) + row_) * 1024 + k0 + cb_;                \
    int g_ = ((row_ >> 1) & 3) << 3;                                                      \
    *(u16x8*)&(DST)[row_ * 32 + (cb_ ^ g_)]       = *(const u16x8*)gp_;                   \
    *(u16x8*)&(DST)[row_ * 32 + ((cb_ + 8) ^ g_)] = *(const u16x8*)(gp_ + 8); }
#endif

// ---------------- converts ----------------
__global__ __launch_bounds__(256) void k_split(const float* __restrict__ s,
                                               u16* __restrict__ hi, u16* __restrict__ lo) {
    size_t i = ((size_t)blockIdx.x * 256 + threadIdx.x) * 4;
    f32x4 v = *(const f32x4*)(s + i);
    u16x4 h, l;
#pragma unroll
    for (int j = 0; j < 4; j++) {
        u16 hh = f2bf(v[j]);
        h[j] = hh;
        l[j] = f2bf(v[j] - bf2f(hh));
    }
    *(u16x4*)(hi + i) = h;
    *(u16x4*)(lo + i) = l;
}

__global__ __launch_bounds__(256) void k_conv(const float* __restrict__ s, u16* __restrict__ d) {
    size_t i = ((size_t)blockIdx.x * 256 + threadIdx.x) * 4;
    f32x4 v = *(const f32x4*)(s + i);
    u16x4 h;
#pragma unroll
    for (int j = 0; j < 4; j++) h[j] = f2bf(v[j]);
    *(u16x4*)(d + i) = h;
}

// wt[m*64+d] = omega[d*256+m] * DH^-0.25, split hi/lo
__global__ __launch_bounds__(256) void k_omega(const float* __restrict__ om,
                                               u16* __restrict__ wh, u16* __restrict__ wl) {
    int i = blockIdx.x * 256 + threadIdx.x; // 16384
    int m = i >> 6, d = i & 63;
    float v = om[d * 256 + m] * 0.35355339059327373f;
    u16 h = f2bf(v);
    wh[i] = h;
    wl[i] = f2bf(v - bf2f(h));
}

__global__ __launch_bounds__(256) void k_zero(float* __restrict__ p, int n) {
    int i = (blockIdx.x * 256 + threadIdx.x) * 4;
    if (i < n) { f32x4 z; z[0]=0.f; z[1]=0.f; z[2]=0.f; z[3]=0.f; *(f32x4*)(p + i) = z; }
}

// ---------------- QKV GEMM: pre-split A/B, swizzled LDS, gload_lds staging ----------------
// Q,K (n0<2048): 3-MFMA split. V (n0>=2048): 1 MFMA hi*hi (bf16-rounded on store anyway).
template <bool STORE_LO>
__global__ __launch_bounds__(256) void k_gemm_qkv(
    const u16* __restrict__ Ah, const u16* __restrict__ Al,
    const u16* __restrict__ Bh, const u16* __restrict__ Bl,
    u16* __restrict__ QKh, u16* __restrict__ QKl, u16* __restrict__ Vb) {
    __shared__ __align__(16) u16 sm[16384]; // 32 KB: 4 x [128][32] tiles
    u16* sAh = sm;
    u16* sAl = sm + 4096;
    u16* sBh = sm + 8192;
    u16* sBl = sm + 12288;
    const int tid = threadIdx.x, wave = tid >> 6, lane = tid & 63;
    const int lr = lane & 15, lk = (lane >> 4) * 8;
    const int m0 = blockIdx.y * 128, n0 = blockIdx.x * 128;
    const int wm = (wave >> 1) * 64, wn = (wave & 1) * 64;
    const int sec = n0 >> 10;
    const bool isV = (sec == 2);

    f32x4 acc[4][4];
#pragma unroll
    for (int i = 0; i < 4; i++)
#pragma unroll
        for (int j = 0; j < 4; j++)
#pragma unroll
            for (int r = 0; r < 4; r++) acc[i][j][r] = 0.f;

    for (int k0 = 0; k0 < 1024; k0 += 32) {
        STAGE_T(sAh, Ah, m0)
        STAGE_T(sBh, Bh, n0)
        if (!isV) {
            STAGE_T(sAl, Al, m0)
            STAGE_T(sBl, Bl, n0)
        }
        __syncthreads();
        s16x8 ah[4], al[4], bh2[4], bl2[4];
#pragma unroll
        for (int f = 0; f < 4; f++) {
            int ra = wm + f * 16 + lr;
            int ca = lk ^ (((ra >> 1) & 3) << 3);
            int rb = wn + f * 16 + lr;
            int cb = lk ^ (((rb >> 1) & 3) << 3);
            ah[f]  = *(const s16x8*)&sAh[ra * 32 + ca];
            bh2[f] = *(const s16x8*)&sBh[rb * 32 + cb];
            if (!isV) {
                al[f]  = *(const s16x8*)&sAl[ra * 32 + ca];
                bl2[f] = *(const s16x8*)&sBl[rb * 32 + cb];
            }
        }
        if (!isV) {
#pragma unroll
            for (int i = 0; i < 4; i++)
#pragma unroll
                for (int j = 0; j < 4; j++) {
                    acc[i][j] = mfma16(ah[i], bh2[j], acc[i][j]);
                    acc[i][j] = mfma16(ah[i], bl2[j], acc[i][j]);
                    acc[i][j] = mfma16(al[i], bh2[j], acc[i][j]);
                }
        } else {
#pragma unroll
            for (int i = 0; i < 4; i++)
#pragma unroll
                for (int j = 0; j < 4; j++)
                    acc[i][j] = mfma16(ah[i], bh2[j], acc[i][j]);
        }
        __syncthreads();
    }

    // epilogue: restage 32-row groups through LDS for coalesced stores
    float* ep = (float*)sm; // [32][132] f32 = 16896 B (fits in 32 KB)
    for (int g = 0; g < 4; g++) {
        __syncthreads();
        if ((wave >> 1) == (g >> 1)) {
#pragma unroll
            for (int fi = 0; fi < 2; fi++) {
                int fm = (g & 1) * 2 + fi;
#pragma unroll
                for (int j = 0; j < 4; j++)
#pragma unroll
                    for (int r = 0; r < 4; r++)
                        ep[(fi * 16 + (lane >> 4) * 4 + r) * 132 + wn + j * 16 + lr] = acc[fm][j][r];
            }
        }
        __syncthreads();
        int row = tid >> 3, c0 = (tid & 7) * 16;
        int grow = m0 + g * 32 + row;
        float v[16];
#pragma unroll
        for (int j = 0; j < 16; j++) v[j] = ep[row * 132 + c0 + j];
        if (sec < 2) {
            u16x8 h0, h1;
#pragma unroll
            for (int j = 0; j < 8; j++) { h0[j] = f2bf(v[j]); h1[j] = f2bf(v[8 + j]); }
            size_t o = (size_t)grow * 2048 + (n0 + c0);
            *(u16x8*)(QKh + o) = h0; *(u16x8*)(QKh + o + 8) = h1;
            if (STORE_LO) {
                u16x8 q0, q1;
#pragma unroll
                for (int j = 0; j < 8; j++) {
                    q0[j] = f2bf(v[j] - bf2f(h0[j]));
                    q1[j] = f2bf(v[8 + j] - bf2f(h1[j]));
                }
                *(u16x8*)(QKl + o) = q0; *(u16x8*)(QKl + o + 8) = q1;
            }
        } else {
            u16x8 h0, h1;
#pragma unroll
            for (int j = 0; j < 8; j++) { h0[j] = f2bf(v[j]); h1[j] = f2bf(v[8 + j]); }
            size_t o = (size_t)grow * 1024 + (n0 - 2048 + c0);
            *(u16x8*)(Vb + o) = h0; *(u16x8*)(Vb + o + 8) = h1;
        }
    }
}

// ---------------- fused phi(K) + KV + Ksum ----------------
template <int NM>
__global__ __launch_bounds__(256) void k_phik_kv(
    const u16* __restrict__ QKh, const u16* __restrict__ QKl,
    const u16* __restrict__ wth, const u16* __restrict__ wtl,
    const u16* __restrict__ Vb, float* __restrict__ KVacc, float* __restrict__ Ksum) {
    __shared__ __align__(16) u16 sKh[64 * 72];
    __shared__ __align__(16) u16 sKl[64 * 72];
    __shared__ __align__(16) u16 sVt[64 * 72];
    __shared__ __align__(16) u16 sKfT[256 * 72];
    __shared__ float snsq[64];
    const int tid = threadIdx.x, wave = tid >> 6, lane = tid & 63;
    const int lr = lane & 15, lk = (lane >> 4) * 8;
    const int kc = blockIdx.x, bh = blockIdx.y;
    const int b = bh >> 4, h = bh & 15;

    s16x8 wbh[4][2], wbl[4][2];
#pragma unroll
    for (int fn = 0; fn < 4; fn++)
#pragma unroll
        for (int ks = 0; ks < 2; ks++) {
            size_t g = (size_t)(wave * 64 + fn * 16 + lr) * 64 + ks * 32 + lk;
            wbh[fn][ks] = *(const s16x8*)(wth + g);
            wbl[fn][ks] = *(const s16x8*)(wtl + g);
        }

    f32x4 akv[4][4];
#pragma unroll
    for (int i = 0; i < 4; i++)
#pragma unroll
        for (int j = 0; j < 4; j++)
#pragma unroll
            for (int r = 0; r < 4; r++) akv[i][j][r] = 0.f;
    float ksm[4] = {0.f, 0.f, 0.f, 0.f};

    for (int it = 0; it < 8; it++) {
        int l0 = kc * 512 + it * 64;
        __syncthreads();
        { // stage K (hi/lo) + nsq
            int row = tid >> 2, c0 = (tid & 3) * 16;
            size_t g = ((size_t)(b * Ll + l0 + row)) * 2048 + 1024 + h * 64 + c0;
            u16x8 h0 = *(const u16x8*)(QKh + g);
            u16x8 h1 = *(const u16x8*)(QKh + g + 8);
            *(u16x8*)&sKh[row * 72 + c0]     = h0;
            *(u16x8*)&sKh[row * 72 + c0 + 8] = h1;
            float s = 0.f;
            if (NM == 3) {
                u16x8 q0 = *(const u16x8*)(QKl + g);
                u16x8 q1 = *(const u16x8*)(QKl + g + 8);
                *(u16x8*)&sKl[row * 72 + c0]     = q0;
                *(u16x8*)&sKl[row * 72 + c0 + 8] = q1;
#pragma unroll
                for (int j = 0; j < 8; j++) {
                    float a = bf2f(h0[j]) + bf2f(q0[j]); s += a * a;
                    float c = bf2f(h1[j]) + bf2f(q1[j]); s += c * c;
                }
            } else {
#pragma unroll
                for (int j = 0; j < 8; j++) {
                    float a = bf2f(h0[j]); s += a * a;
                    float c = bf2f(h1[j]); s += c * c;
                }
            }
            s += __shfl_xor(s, 1); s += __shfl_xor(s, 2);
            if ((tid & 3) == 0) snsq[row] = s * 0.0625f;
        }
        { // stage V transposed
            int l = tid >> 2, d0 = (tid & 3) * 16;
            size_t g = ((size_t)(b * Ll + l0 + l)) * 1024 + h * 64 + d0;
            u16x8 v0 = *(const u16x8*)(Vb + g);
            u16x8 v1 = *(const u16x8*)(Vb + g + 8);
#pragma unroll
            for (int j = 0; j < 8; j++) {
                sVt[(d0 + j) * 72 + l] = v0[j];
                sVt[(d0 + 8 + j) * 72 + l] = v1[j];
            }
        }
        __syncthreads();
#pragma unroll
        for (int fm = 0; fm < 4; fm++) {
            f32x4 ap[4];
#pragma unroll
            for (int fn = 0; fn < 4; fn++)
#pragma unroll
                for (int r = 0; r < 4; r++) ap[fn][r] = 0.f;
#pragma unroll
            for (int ks = 0; ks < 2; ks++) {
                s16x8 aH = *(const s16x8*)&sKh[(fm * 16 + lr) * 72 + ks * 32 + lk];
                s16x8 aL;
                if (NM == 3) aL = *(const s16x8*)&sKl[(fm * 16 + lr) * 72 + ks * 32 + lk];
#pragma unroll
                for (int fn = 0; fn < 4; fn++) {
                    ap[fn] = mfma16(aH, wbh[fn][ks], ap[fn]);
                    ap[fn] = mfma16(aH, wbl[fn][ks], ap[fn]);
                    if (NM == 3) ap[fn] = mfma16(aL, wbh[fn][ks], ap[fn]);
                }
            }
#pragma unroll
            for (int fn = 0; fn < 4; fn++) {
                u16x4 pk;
#pragma unroll
                for (int r = 0; r < 4; r++) {
                    float ns = snsq[fm * 16 + (lane >> 4) * 4 + r];
                    float val = __expf(ap[fn][r] - ns) * 0.0625f;
                    ksm[fn] += val;
                    pk[r] = f2bf(val);
                }
                *(u16x4*)&sKfT[(wave * 64 + fn * 16 + lr) * 72 + fm * 16 + (lane >> 4) * 4] = pk;
            }
        }
#pragma unroll
        for (int ks = 0; ks < 2; ks++) {
            s16x8 a4[4], b4[4];
#pragma unroll
            for (int f = 0; f < 4; f++) {
                a4[f] = *(const s16x8*)&sKfT[(wave * 64 + f * 16 + lr) * 72 + ks * 32 + lk];
                b4[f] = *(const s16x8*)&sVt[(f * 16 + lr) * 72 + ks * 32 + lk];
            }
#pragma unroll
            for (int fm = 0; fm < 4; fm++)
#pragma unroll
                for (int fn = 0; fn < 4; fn++)
                    akv[fm][fn] = mfma16(a4[fm], b4[fn], akv[fm][fn]);
        }
    }
#pragma unroll
    for (int fm = 0; fm < 4; fm++)
#pragma unroll
        for (int fn = 0; fn < 4; fn++)
#pragma unroll
            for (int r = 0; r < 4; r++) {
                int m = wave * 64 + fm * 16 + (lane >> 4) * 4 + r;
                int d = fn * 16 + lr;
                atomicAdd(&KVacc[((size_t)bh << 14) + m * 64 + d], akv[fm][fn][r]);
            }
#pragma unroll
    for (int fn = 0; fn < 4; fn++) {
        ksm[fn] += __shfl_xor(ksm[fn], 16);
        ksm[fn] += __shfl_xor(ksm[fn], 32);
    }
    if (lane < 16) {
#pragma unroll
        for (int fn = 0; fn < 4; fn++)
            atomicAdd(&Ksum[bh * 256 + wave * 64 + fn * 16 + lane], ksm[fn]);
    }
}

// KVt[bh][d][m] = bf16(KVacc[bh][m][d])
__global__ __launch_bounds__(256) void k_kvt(const float* __restrict__ KVacc, u16* __restrict__ KVt) {
    int i = blockIdx.x * 256 + threadIdx.x;
    int bh = i >> 14, dd = (i >> 8) & 63, m = i & 255;
    KVt[i] = f2bf(KVacc[((size_t)bh << 14) + m * 64 + dd]);
}

// ---------------- fused phi(Q) + norm + attn ----------------
template <int NM>
__global__ __launch_bounds__(512) void k_phiq_attn(
    const u16* __restrict__ QKh, const u16* __restrict__ QKl,
    const u16* __restrict__ wth, const u16* __restrict__ wtl,
    const u16* __restrict__ KVt, const float* __restrict__ Ksum,
    u16* __restrict__ attn) {
    __shared__ __align__(16) u16 sQh[64 * 72];
    __shared__ __align__(16) u16 sQl[64 * 72];
    __shared__ __align__(16) u16 sQf[64 * 264];
    __shared__ float sKs[256];
    __shared__ float snsq[64];
    __shared__ float snorm[64];
    const int tid = threadIdx.x, wave = tid >> 6, lane = tid & 63;
    const int lr = lane & 15, lk = (lane >> 4) * 8;
    const int bh = blockIdx.y, b = bh >> 4, h = bh & 15;
    const int mq = wave & 3;
    const int lh = wave >> 2;
    const int af = wave & 3;
    const int ad = wave >> 2;

    s16x8 wbh[4][2], wbl[4][2];
#pragma unroll
    for (int fn = 0; fn < 4; fn++)
#pragma unroll
        for (int ks = 0; ks < 2; ks++) {
            size_t g = (size_t)(mq * 64 + fn * 16 + lr) * 64 + ks * 32 + lk;
            wbh[fn][ks] = *(const s16x8*)(wth + g);
            wbl[fn][ks] = *(const s16x8*)(wtl + g);
        }
    s16x8 kvb[2][8];
#pragma unroll
    for (int fn = 0; fn < 2; fn++)
#pragma unroll
        for (int ks = 0; ks < 8; ks++)
            kvb[fn][ks] = *(const s16x8*)(KVt + ((size_t)bh << 14) +
                                          (size_t)(ad * 32 + fn * 16 + lr) * 256 + ks * 32 + lk);
    if (tid < 256) sKs[tid] = Ksum[bh * 256 + tid];

    for (int st = 0; st < 2; st++) {
        const int l0 = (blockIdx.x * 2 + st) * 64;
        __syncthreads();
        {
            int row = tid >> 3, c0 = (tid & 7) * 8;
            size_t g = ((size_t)(b * Ll + l0 + row)) * 2048 + h * 64 + c0;
            u16x8 vh = *(const u16x8*)(QKh + g);
            *(u16x8*)&sQh[row * 72 + c0] = vh;
            float s = 0.f;
            if (NM == 3) {
                u16x8 vl = *(const u16x8*)(QKl + g);
                *(u16x8*)&sQl[row * 72 + c0] = vl;
#pragma unroll
                for (int j = 0; j < 8; j++) { float a = bf2f(vh[j]) + bf2f(vl[j]); s += a * a; }
            } else {
#pragma unroll
                for (int j = 0; j < 8; j++) { float a = bf2f(vh[j]); s += a * a; }
            }
            s += __shfl_xor(s, 1); s += __shfl_xor(s, 2); s += __shfl_xor(s, 4);
            if ((tid & 7) == 0) snsq[row] = s * 0.0625f;
        }
        __syncthreads();
#pragma unroll
        for (int fm = 0; fm < 2; fm++) {
            f32x4 ap[4];
#pragma unroll
            for (int fn = 0; fn < 4; fn++)
#pragma unroll
                for (int r = 0; r < 4; r++) ap[fn][r] = 0.f;
#pragma unroll
            for (int ks = 0; ks < 2; ks++) {
                s16x8 aH = *(const s16x8*)&sQh[(lh * 32 + fm * 16 + lr) * 72 + ks * 32 + lk];
                s16x8 aL;
                if (NM == 3) aL = *(const s16x8*)&sQl[(lh * 32 + fm * 16 + lr) * 72 + ks * 32 + lk];
#pragma unroll
                for (int fn = 0; fn < 4; fn++) {
                    ap[fn] = mfma16(aH, wbh[fn][ks], ap[fn]);
                    ap[fn] = mfma16(aH, wbl[fn][ks], ap[fn]);
                    if (NM == 3) ap[fn] = mfma16(aL, wbh[fn][ks], ap[fn]);
                }
            }
#pragma unroll
            for (int fn = 0; fn < 4; fn++)
#pragma unroll
                for (int r = 0; r < 4; r++) {
                    int l = lh * 32 + fm * 16 + (lane >> 4) * 4 + r;
                    int m = mq * 64 + fn * 16 + lr;
                    sQf[l * 264 + m] = f2bf(__expf(ap[fn][r] - snsq[l]) * 0.0625f);
                }
        }
        __syncthreads();
        {
            int l = tid >> 3, m0 = (tid & 7) * 32;
            float s = 0.f;
#pragma unroll
            for (int j = 0; j < 32; j++) s += bf2f(sQf[l * 264 + m0 + j]) * sKs[m0 + j];
            s += __shfl_xor(s, 1); s += __shfl_xor(s, 2); s += __shfl_xor(s, 4);
            if ((tid & 7) == 0) snorm[l] = s;
        }
        f32x4 aa[2];
#pragma unroll
        for (int fn = 0; fn < 2; fn++)
#pragma unroll
            for (int r = 0; r < 4; r++) aa[fn][r] = 0.f;
#pragma unroll
        for (int ks = 0; ks < 8; ks++) {
            s16x8 a = *(const s16x8*)&sQf[(af * 16 + lr) * 264 + ks * 32 + lk];
            aa[0] = mfma16(a, kvb[0][ks], aa[0]);
            aa[1] = mfma16(a, kvb[1][ks], aa[1]);
        }
        __syncthreads();
        float* ep = (float*)sQf; // [64][68]
#pragma unroll
        for (int fn = 0; fn < 2; fn++)
#pragma unroll
            for (int r = 0; r < 4; r++) {
                int l = af * 16 + (lane >> 4) * 4 + r;
                int d = ad * 32 + fn * 16 + lr;
                ep[l * 68 + d] = aa[fn][r];
            }
        __syncthreads();
        {
            int l = tid >> 3, d0 = (tid & 7) * 8;
            float inv = 1.0f / fmaxf(snorm[l], 1e-6f);
            u16x8 o;
#pragma unroll
            for (int j = 0; j < 8; j++) o[j] = f2bf(ep[l * 68 + d0 + j] * inv);
            *(u16x8*)(attn + ((size_t)(b * Ll + l0 + l)) * 1024 + h * 64 + d0) = o;
        }
    }
}

// ---------------- final GEMM: attn @ Wo^T + bo -> f32 out ----------------
__global__ __launch_bounds__(256) void k_gemm_out(const u16* __restrict__ Ab, const u16* __restrict__ Bw,
                                                  const float* __restrict__ bias, float* __restrict__ outp) {
    __shared__ __align__(16) u16 sm[8448]; // 16896 B: 2 x [128][32] tiles + epilogue fits
    u16* sA = sm;
    u16* sB = sm + 4096;
    const int tid = threadIdx.x, wave = tid >> 6, lane = tid & 63;
    const int lr = lane & 15, lk = (lane >> 4) * 8;
    const int m0 = blockIdx.y * 128, n0 = blockIdx.x * 128;
    const int wm = (wave >> 1) * 64, wn = (wave & 1) * 64;

    f32x4 acc[4][4];
#pragma unroll
    for (int i = 0; i < 4; i++)
#pragma unroll
        for (int j = 0; j < 4; j++)
#pragma unroll
            for (int r = 0; r < 4; r++) acc[i][j][r] = 0.f;

    for (int k0 = 0; k0 < 1024; k0 += 32) {
        STAGE_T(sA, Ab, m0)
        STAGE_T(sB, Bw, n0)
        __syncthreads();
        s16x8 a[4], bb[4];
#pragma unroll
        for (int f = 0; f < 4; f++) {
            int ra = wm + f * 16 + lr;
            int ca = lk ^ (((ra >> 1) & 3) << 3);
            int rb = wn + f * 16 + lr;
            int cb = lk ^ (((rb >> 1) & 3) << 3);
            a[f]  = *(const s16x8*)&sA[ra * 32 + ca];
            bb[f] = *(const s16x8*)&sB[rb * 32 + cb];
        }
#pragma unroll
        for (int i = 0; i < 4; i++)
#pragma unroll
            for (int j = 0; j < 4; j++)
                acc[i][j] = mfma16(a[i], bb[j], acc[i][j]);
        __syncthreads();
    }
    float* ep = (float*)sm; // [32][132]
    for (int g = 0; g < 4; g++) {
        __syncthreads();
        if ((wave >> 1) == (g >> 1)) {
#pragma unroll
            for (int fi = 0; fi < 2; fi++) {
                int fm = (g & 1) * 2 + fi;
#pragma unroll
                for (int j = 0; j < 4; j++)
#pragma unroll
                    for (int r = 0; r < 4; r++)
                        ep[(fi * 16 + (lane >> 4) * 4 + r) * 132 + wn + j * 16 + lr] = acc[fm][j][r];
            }
        }
        __syncthreads();
        int row = tid >> 3, c0 = (tid & 7) * 16;
        int grow = m0 + g * 32 + row;
        float vv[16];
#pragma unroll
        for (int j = 0; j < 16; j++) vv[j] = ep[row * 132 + c0 + j] + bias[n0 + c0 + j];
#pragma unroll
        for (int p = 0; p < 4; p++) {
            f32x4 t;
#pragma unroll
            for (int q = 0; q < 4; q++) t[q] = vv[p * 4 + q];
            *(f32x4*)(outp + (size_t)grow * 1024 + n0 + c0 + p * 4) = t;
        }
    }
}

extern "C" void kernel_launch(void* const* d_in, const int* in_sizes, int n_in,
                              void* d_out, int out_size, void* d_ws, size_t ws_size,
                              hipStream_t stream) {
    (void)in_sizes; (void)n_in; (void)out_size;
    const float* x  = (const float*)d_in[0];
    const float* Wq = (const float*)d_in[1];
    const float* Wk = (const float*)d_in[2];
    const float* Wv = (const float*)d_in[3];
    const float* Wo = (const float*)d_in[4];
    const float* bo = (const float*)d_in[5];
    const float* om = (const float*)d_in[6];

    // Path A (split Q/K storage) needs 255,983,616 B; Path B needs 188,874,752 B.
    const bool pa = ws_size >= (size_t)255983616ull;

    char* w = (char*)d_ws;
    size_t o = 0;
    auto take = [&](size_t n) { char* p = w + o; o += n; return p; };
    u16* QKh = (u16*)take(67108864);
    u16* QKl = pa ? (u16*)take(67108864) : QKh; // alias in path B (never read)
    u16* Vb  = (u16*)take(33554432);
    u16* xh  = (u16*)take(33554432);
    u16* xl  = (u16*)take(33554432);
    u16* Wh  = (u16*)take(6291456);
    u16* Wl  = (u16*)take(6291456);
    u16* Wob = (u16*)take(2097152);
    u16* wth = (u16*)take(32768);
    u16* wtl = (u16*)take(32768);
    float* KVacc = (float*)take(4194304);
    float* Ksum  = (float*)take(65536);   // contiguous after KVacc for k_zero
    u16* KVt = (u16*)take(2097152);
    u16* attn = Vb; // alias: V dead after k_phik_kv

    k_split<<<16384, 256, 0, stream>>>(x, xh, xl);
    k_split<<<1024, 256, 0, stream>>>(Wq, Wh, Wl);
    k_split<<<1024, 256, 0, stream>>>(Wk, Wh + 1048576, Wl + 1048576);
    k_split<<<1024, 256, 0, stream>>>(Wv, Wh + 2097152, Wl + 2097152);
    k_conv<<<1024, 256, 0, stream>>>(Wo, Wob);
    k_omega<<<64, 256, 0, stream>>>(om, wth, wtl);
    k_zero<<<1040, 256, 0, stream>>>(KVacc, 1064960); // KVacc + Ksum

    if (pa) k_gemm_qkv<true ><<<dim3(24, 128), 256, 0, stream>>>(xh, xl, Wh, Wl, QKh, QKl, Vb);
    else    k_gemm_qkv<false><<<dim3(24, 128), 256, 0, stream>>>(xh, xl, Wh, Wl, QKh, QKl, Vb);

    if (pa) k_phik_kv<3><<<dim3(8, 64), 256, 0, stream>>>(QKh, QKl, wth, wtl, Vb, KVacc, Ksum);
    else    k_phik_kv<2><<<dim3(8, 64), 256, 0, stream>>>(QKh, QKl, wth, wtl, Vb, KVacc, Ksum);

    k_kvt<<<4096, 256, 0, stream>>>(KVacc, KVt);

    if (pa) k_phiq_attn<3><<<dim3(32, 64), 512, 0, stream>>>(QKh, QKl, wth, wtl, KVt, Ksum, attn);
    else    k_phiq_attn<2><<<dim3(32, 64), 512, 0, stream>>>(QKh, QKl, wth, wtl, KVt, Ksum, attn);

    k_gemm_out<<<dim3(8, 128), 256, 0, stream>>>(attn, Wob, bo, (float*)d_out);
}

// Round 4
// 569.873 us; speedup vs baseline: 1.1916x; 1.0400x over previous
//
#include <hip/hip_runtime.h>

typedef unsigned short u16;
typedef __attribute__((ext_vector_type(4))) float f32x4;
typedef __attribute__((ext_vector_type(8))) short s16x8;
typedef __attribute__((ext_vector_type(4))) u16   u16x4;
typedef __attribute__((ext_vector_type(8))) u16   u16x8;

#define DEV static __device__ __forceinline__

constexpr int Ll = 4096;

DEV float bf2f(u16 v) { unsigned u = ((unsigned)v) << 16; float f; __builtin_memcpy(&f, &u, 4); return f; }
DEV u16 f2bf(float f) { // round-to-nearest-even
    unsigned u; __builtin_memcpy(&u, &f, 4);
    u += 0x7fffu + ((u >> 16) & 1u);
    return (u16)(u >> 16);
}

DEV f32x4 mfma16(s16x8 a, s16x8 b, f32x4 c) {
    return __builtin_amdgcn_mfma_f32_16x16x32_bf16(a, b, c, 0, 0, 0);
}

#if defined(__has_builtin)
#if __has_builtin(__builtin_amdgcn_global_load_lds)
#define HAS_GLLDS 1
#endif
#endif
#ifndef HAS_GLLDS
#define HAS_GLLDS 0
#endif

// Stage a [128][32] u16 tile (8KB) into DST with XOR-swizzle col^(((row>>1)&3)<<3).
// gload_lds path: linear LDS dest (wave-uniform base + lane*16), inverse-swizzled
// global source (same involution). Fallback: reg-staged swizzled writes.
#if HAS_GLLDS
#define STAGE_T(DST, SRC, ROWBASE, KK)                                                    \
  { _Pragma("unroll") for (int j_ = 0; j_ < 2; j_++) {                                    \
      int row_ = wave * 32 + j_ * 16 + (lane >> 2);                                       \
      int col_ = ((lane & 3) ^ ((row_ >> 1) & 3)) * 8;                                    \
      const u16* gp_ = (SRC) + (size_t)((ROWBASE) + row_) * 1024 + (KK) + col_;           \
      __builtin_amdgcn_global_load_lds(                                                   \
          (const __attribute__((address_space(1))) unsigned int*)gp_,                     \
          (__attribute__((address_space(3))) unsigned int*)((DST) + (wave * 2 + j_) * 512), \
          16, 0, 0); } }
#else
#define STAGE_T(DST, SRC, ROWBASE, KK)                                                    \
  { int row_ = tid >> 1, cb_ = (tid & 1) * 16;                                            \
    const u16* gp_ = (SRC) + (size_t)((ROWBASE) + row_) * 1024 + (KK) + cb_;              \
    int g_ = ((row_ >> 1) & 3) << 3;                                                      \
    *(u16x8*)&(DST)[row_ * 32 + (cb_ ^ g_)]       = *(const u16x8*)gp_;                   \
    *(u16x8*)&(DST)[row_ * 32 + ((cb_ + 8) ^ g_)] = *(const u16x8*)(gp_ + 8); }
#endif

// ---------------- converts ----------------
__global__ __launch_bounds__(256) void k_split(const float* __restrict__ s,
                                               u16* __restrict__ hi, u16* __restrict__ lo) {
    size_t i = ((size_t)blockIdx.x * 256 + threadIdx.x) * 4;
    f32x4 v = *(const f32x4*)(s + i);
    u16x4 h, l;
#pragma unroll
    for (int j = 0; j < 4; j++) {
        u16 hh = f2bf(v[j]);
        h[j] = hh;
        l[j] = f2bf(v[j] - bf2f(hh));
    }
    *(u16x4*)(hi + i) = h;
    *(u16x4*)(lo + i) = l;
}

__global__ __launch_bounds__(256) void k_conv(const float* __restrict__ s, u16* __restrict__ d) {
    size_t i = ((size_t)blockIdx.x * 256 + threadIdx.x) * 4;
    f32x4 v = *(const f32x4*)(s + i);
    u16x4 h;
#pragma unroll
    for (int j = 0; j < 4; j++) h[j] = f2bf(v[j]);
    *(u16x4*)(d + i) = h;
}

// wt[m*64+d] = omega[d*256+m] * DH^-0.25, split hi/lo
__global__ __launch_bounds__(256) void k_omega(const float* __restrict__ om,
                                               u16* __restrict__ wh, u16* __restrict__ wl) {
    int i = blockIdx.x * 256 + threadIdx.x; // 16384
    int m = i >> 6, d = i & 63;
    float v = om[d * 256 + m] * 0.35355339059327373f;
    u16 h = f2bf(v);
    wh[i] = h;
    wl[i] = f2bf(v - bf2f(h));
}

__global__ __launch_bounds__(256) void k_zero(float* __restrict__ p, int n) {
    int i = (blockIdx.x * 256 + threadIdx.x) * 4;
    if (i < n) { f32x4 z; z[0]=0.f; z[1]=0.f; z[2]=0.f; z[3]=0.f; *(f32x4*)(p + i) = z; }
}

// ---------------- QKV GEMM: pre-split A/B, swizzled LDS, gload_lds, DOUBLE-BUFFERED ----------------
// Q,K (n0<2048): 3-MFMA split. V (n0>=2048): 1 MFMA hi*hi (bf16-rounded on store anyway).
template <bool STORE_LO>
__global__ __launch_bounds__(256) void k_gemm_qkv(
    const u16* __restrict__ Ah, const u16* __restrict__ Al,
    const u16* __restrict__ Bh, const u16* __restrict__ Bl,
    u16* __restrict__ QKh, u16* __restrict__ QKl, u16* __restrict__ Vb) {
    __shared__ __align__(16) u16 sm[32768]; // 64 KB: 2 buffers x 4 x [128][32] tiles
    const int tid = threadIdx.x, wave = tid >> 6, lane = tid & 63;
    const int lr = lane & 15, lk = (lane >> 4) * 8;
    const int m0 = blockIdx.y * 128, n0 = blockIdx.x * 128;
    const int wm = (wave >> 1) * 64, wn = (wave & 1) * 64;
    const int sec = n0 >> 10;
    const bool isV = (sec == 2);
    constexpr int TILE = 4096, BUF = 16384;

    // k-invariant fragment offsets (swizzled)
    int aoff[4], boff[4];
#pragma unroll
    for (int f = 0; f < 4; f++) {
        int ra = wm + f * 16 + lr;
        aoff[f] = ra * 32 + (lk ^ (((ra >> 1) & 3) << 3));
        int rb = wn + f * 16 + lr;
        boff[f] = rb * 32 + (lk ^ (((rb >> 1) & 3) << 3));
    }

    f32x4 acc[4][4];
#pragma unroll
    for (int i = 0; i < 4; i++)
#pragma unroll
        for (int j = 0; j < 4; j++)
#pragma unroll
            for (int r = 0; r < 4; r++) acc[i][j][r] = 0.f;

    // prologue: stage k=0 into buffer 0
    STAGE_T(sm + 0 * TILE, Ah, m0, 0)
    STAGE_T(sm + 2 * TILE, Bh, n0, 0)
    if (!isV) {
        STAGE_T(sm + 1 * TILE, Al, m0, 0)
        STAGE_T(sm + 3 * TILE, Bl, n0, 0)
    }
    __syncthreads();

    int cur = 0;
    for (int k0 = 0; k0 < 1024; k0 += 32) {
        u16* buf  = sm + cur * BUF;
        u16* nbuf = sm + (cur ^ 1) * BUF;
        if (k0 + 32 < 1024) { // issue next tile's loads BEFORE computing current
            STAGE_T(nbuf + 0 * TILE, Ah, m0, k0 + 32)
            STAGE_T(nbuf + 2 * TILE, Bh, n0, k0 + 32)
            if (!isV) {
                STAGE_T(nbuf + 1 * TILE, Al, m0, k0 + 32)
                STAGE_T(nbuf + 3 * TILE, Bl, n0, k0 + 32)
            }
        }
        s16x8 ah[4], al[4], bh2[4], bl2[4];
#pragma unroll
        for (int f = 0; f < 4; f++) {
            ah[f]  = *(const s16x8*)&buf[aoff[f]];
            bh2[f] = *(const s16x8*)&buf[2 * TILE + boff[f]];
            if (!isV) {
                al[f]  = *(const s16x8*)&buf[TILE + aoff[f]];
                bl2[f] = *(const s16x8*)&buf[3 * TILE + boff[f]];
            }
        }
        if (!isV) {
#pragma unroll
            for (int i = 0; i < 4; i++)
#pragma unroll
                for (int j = 0; j < 4; j++) {
                    acc[i][j] = mfma16(ah[i], bh2[j], acc[i][j]);
                    acc[i][j] = mfma16(ah[i], bl2[j], acc[i][j]);
                    acc[i][j] = mfma16(al[i], bh2[j], acc[i][j]);
                }
        } else {
#pragma unroll
            for (int i = 0; i < 4; i++)
#pragma unroll
                for (int j = 0; j < 4; j++)
                    acc[i][j] = mfma16(ah[i], bh2[j], acc[i][j]);
        }
        __syncthreads(); // drains next-tile loads (issued ~1 MFMA-phase ago) + barrier
        cur ^= 1;
    }

    // epilogue: restage 32-row groups through LDS for coalesced stores
    float* ep = (float*)sm; // [32][132] f32 = 16896 B
    for (int g = 0; g < 4; g++) {
        __syncthreads();
        if ((wave >> 1) == (g >> 1)) {
#pragma unroll
            for (int fi = 0; fi < 2; fi++) {
                int fm = (g & 1) * 2 + fi;
#pragma unroll
                for (int j = 0; j < 4; j++)
#pragma unroll
                    for (int r = 0; r < 4; r++)
                        ep[(fi * 16 + (lane >> 4) * 4 + r) * 132 + wn + j * 16 + lr] = acc[fm][j][r];
            }
        }
        __syncthreads();
        int row = tid >> 3, c0 = (tid & 7) * 16;
        int grow = m0 + g * 32 + row;
        float v[16];
#pragma unroll
        for (int j = 0; j < 16; j++) v[j] = ep[row * 132 + c0 + j];
        if (sec < 2) {
            u16x8 h0, h1;
#pragma unroll
            for (int j = 0; j < 8; j++) { h0[j] = f2bf(v[j]); h1[j] = f2bf(v[8 + j]); }
            size_t o = (size_t)grow * 2048 + (n0 + c0);
            *(u16x8*)(QKh + o) = h0; *(u16x8*)(QKh + o + 8) = h1;
            if (STORE_LO) {
                u16x8 q0, q1;
#pragma unroll
                for (int j = 0; j < 8; j++) {
                    q0[j] = f2bf(v[j] - bf2f(h0[j]));
                    q1[j] = f2bf(v[8 + j] - bf2f(h1[j]));
                }
                *(u16x8*)(QKl + o) = q0; *(u16x8*)(QKl + o + 8) = q1;
            }
        } else {
            u16x8 h0, h1;
#pragma unroll
            for (int j = 0; j < 8; j++) { h0[j] = f2bf(v[j]); h1[j] = f2bf(v[8 + j]); }
            size_t o = (size_t)grow * 1024 + (n0 - 2048 + c0);
            *(u16x8*)(Vb + o) = h0; *(u16x8*)(Vb + o + 8) = h1;
        }
    }
}

// ---------------- fused phi(K) + KV + Ksum ----------------
template <int NM>
__global__ __launch_bounds__(256) void k_phik_kv(
    const u16* __restrict__ QKh, const u16* __restrict__ QKl,
    const u16* __restrict__ wth, const u16* __restrict__ wtl,
    const u16* __restrict__ Vb, float* __restrict__ KVacc, float* __restrict__ Ksum) {
    __shared__ __align__(16) u16 sKh[64 * 72];
    __shared__ __align__(16) u16 sKl[64 * 72];
    __shared__ __align__(16) u16 sVt[64 * 72];
    __shared__ __align__(16) u16 sKfT[256 * 72];
    __shared__ float snsq[64];
    const int tid = threadIdx.x, wave = tid >> 6, lane = tid & 63;
    const int lr = lane & 15, lk = (lane >> 4) * 8;
    const int kc = blockIdx.x, bh = blockIdx.y;
    const int b = bh >> 4, h = bh & 15;

    s16x8 wbh[4][2], wbl[4][2];
#pragma unroll
    for (int fn = 0; fn < 4; fn++)
#pragma unroll
        for (int ks = 0; ks < 2; ks++) {
            size_t g = (size_t)(wave * 64 + fn * 16 + lr) * 64 + ks * 32 + lk;
            wbh[fn][ks] = *(const s16x8*)(wth + g);
            wbl[fn][ks] = *(const s16x8*)(wtl + g);
        }

    f32x4 akv[4][4];
#pragma unroll
    for (int i = 0; i < 4; i++)
#pragma unroll
        for (int j = 0; j < 4; j++)
#pragma unroll
            for (int r = 0; r < 4; r++) akv[i][j][r] = 0.f;
    float ksm[4] = {0.f, 0.f, 0.f, 0.f};

    for (int it = 0; it < 8; it++) {
        int l0 = kc * 512 + it * 64;
        __syncthreads();
        { // stage K (hi/lo) + nsq
            int row = tid >> 2, c0 = (tid & 3) * 16;
            size_t g = ((size_t)(b * Ll + l0 + row)) * 2048 + 1024 + h * 64 + c0;
            u16x8 h0 = *(const u16x8*)(QKh + g);
            u16x8 h1 = *(const u16x8*)(QKh + g + 8);
            *(u16x8*)&sKh[row * 72 + c0]     = h0;
            *(u16x8*)&sKh[row * 72 + c0 + 8] = h1;
            float s = 0.f;
            if (NM == 3) {
                u16x8 q0 = *(const u16x8*)(QKl + g);
                u16x8 q1 = *(const u16x8*)(QKl + g + 8);
                *(u16x8*)&sKl[row * 72 + c0]     = q0;
                *(u16x8*)&sKl[row * 72 + c0 + 8] = q1;
#pragma unroll
                for (int j = 0; j < 8; j++) {
                    float a = bf2f(h0[j]) + bf2f(q0[j]); s += a * a;
                    float c = bf2f(h1[j]) + bf2f(q1[j]); s += c * c;
                }
            } else {
#pragma unroll
                for (int j = 0; j < 8; j++) {
                    float a = bf2f(h0[j]); s += a * a;
                    float c = bf2f(h1[j]); s += c * c;
                }
            }
            s += __shfl_xor(s, 1); s += __shfl_xor(s, 2);
            if ((tid & 3) == 0) snsq[row] = s * 0.0625f;
        }
        { // stage V transposed
            int l = tid >> 2, d0 = (tid & 3) * 16;
            size_t g = ((size_t)(b * Ll + l0 + l)) * 1024 + h * 64 + d0;
            u16x8 v0 = *(const u16x8*)(Vb + g);
            u16x8 v1 = *(const u16x8*)(Vb + g + 8);
#pragma unroll
            for (int j = 0; j < 8; j++) {
                sVt[(d0 + j) * 72 + l] = v0[j];
                sVt[(d0 + 8 + j) * 72 + l] = v1[j];
            }
        }
        __syncthreads();
#pragma unroll
        for (int fm = 0; fm < 4; fm++) {
            f32x4 ap[4];
#pragma unroll
            for (int fn = 0; fn < 4; fn++)
#pragma unroll
                for (int r = 0; r < 4; r++) ap[fn][r] = 0.f;
#pragma unroll
            for (int ks = 0; ks < 2; ks++) {
                s16x8 aH = *(const s16x8*)&sKh[(fm * 16 + lr) * 72 + ks * 32 + lk];
                s16x8 aL;
                if (NM == 3) aL = *(const s16x8*)&sKl[(fm * 16 + lr) * 72 + ks * 32 + lk];
#pragma unroll
                for (int fn = 0; fn < 4; fn++) {
                    ap[fn] = mfma16(aH, wbh[fn][ks], ap[fn]);
                    ap[fn] = mfma16(aH, wbl[fn][ks], ap[fn]);
                    if (NM == 3) ap[fn] = mfma16(aL, wbh[fn][ks], ap[fn]);
                }
            }
#pragma unroll
            for (int fn = 0; fn < 4; fn++) {
                u16x4 pk;
#pragma unroll
                for (int r = 0; r < 4; r++) {
                    float ns = snsq[fm * 16 + (lane >> 4) * 4 + r];
                    float val = __expf(ap[fn][r] - ns) * 0.0625f;
                    ksm[fn] += val;
                    pk[r] = f2bf(val);
                }
                *(u16x4*)&sKfT[(wave * 64 + fn * 16 + lr) * 72 + fm * 16 + (lane >> 4) * 4] = pk;
            }
        }
#pragma unroll
        for (int ks = 0; ks < 2; ks++) {
            s16x8 a4[4], b4[4];
#pragma unroll
            for (int f = 0; f < 4; f++) {
                a4[f] = *(const s16x8*)&sKfT[(wave * 64 + f * 16 + lr) * 72 + ks * 32 + lk];
                b4[f] = *(const s16x8*)&sVt[(f * 16 + lr) * 72 + ks * 32 + lk];
            }
#pragma unroll
            for (int fm = 0; fm < 4; fm++)
#pragma unroll
                for (int fn = 0; fn < 4; fn++)
                    akv[fm][fn] = mfma16(a4[fm], b4[fn], akv[fm][fn]);
        }
    }
#pragma unroll
    for (int fm = 0; fm < 4; fm++)
#pragma unroll
        for (int fn = 0; fn < 4; fn++)
#pragma unroll
            for (int r = 0; r < 4; r++) {
                int m = wave * 64 + fm * 16 + (lane >> 4) * 4 + r;
                int d = fn * 16 + lr;
                atomicAdd(&KVacc[((size_t)bh << 14) + m * 64 + d], akv[fm][fn][r]);
            }
#pragma unroll
    for (int fn = 0; fn < 4; fn++) {
        ksm[fn] += __shfl_xor(ksm[fn], 16);
        ksm[fn] += __shfl_xor(ksm[fn], 32);
    }
    if (lane < 16) {
#pragma unroll
        for (int fn = 0; fn < 4; fn++)
            atomicAdd(&Ksum[bh * 256 + wave * 64 + fn * 16 + lane], ksm[fn]);
    }
}

// KVt[bh][d][m] = bf16(KVacc[bh][m][d])
__global__ __launch_bounds__(256) void k_kvt(const float* __restrict__ KVacc, u16* __restrict__ KVt) {
    int i = blockIdx.x * 256 + threadIdx.x;
    int bh = i >> 14, dd = (i >> 8) & 63, m = i & 255;
    KVt[i] = f2bf(KVacc[((size_t)bh << 14) + m * 64 + dd]);
}

// ---------------- fused phi(Q) + norm + attn ----------------
template <int NM>
__global__ __launch_bounds__(512) void k_phiq_attn(
    const u16* __restrict__ QKh, const u16* __restrict__ QKl,
    const u16* __restrict__ wth, const u16* __restrict__ wtl,
    const u16* __restrict__ KVt, const float* __restrict__ Ksum,
    u16* __restrict__ attn) {
    __shared__ __align__(16) u16 sQh[64 * 72];
    __shared__ __align__(16) u16 sQl[64 * 72];
    __shared__ __align__(16) u16 sQf[64 * 264];
    __shared__ float sKs[256];
    __shared__ float snsq[64];
    __shared__ float snorm[64];
    const int tid = threadIdx.x, wave = tid >> 6, lane = tid & 63;
    const int lr = lane & 15, lk = (lane >> 4) * 8;
    const int bh = blockIdx.y, b = bh >> 4, h = bh & 15;
    const int mq = wave & 3;
    const int lh = wave >> 2;
    const int af = wave & 3;
    const int ad = wave >> 2;

    s16x8 wbh[4][2], wbl[4][2];
#pragma unroll
    for (int fn = 0; fn < 4; fn++)
#pragma unroll
        for (int ks = 0; ks < 2; ks++) {
            size_t g = (size_t)(mq * 64 + fn * 16 + lr) * 64 + ks * 32 + lk;
            wbh[fn][ks] = *(const s16x8*)(wth + g);
            wbl[fn][ks] = *(const s16x8*)(wtl + g);
        }
    s16x8 kvb[2][8];
#pragma unroll
    for (int fn = 0; fn < 2; fn++)
#pragma unroll
        for (int ks = 0; ks < 8; ks++)
            kvb[fn][ks] = *(const s16x8*)(KVt + ((size_t)bh << 14) +
                                          (size_t)(ad * 32 + fn * 16 + lr) * 256 + ks * 32 + lk);
    if (tid < 256) sKs[tid] = Ksum[bh * 256 + tid];

    for (int st = 0; st < 2; st++) {
        const int l0 = (blockIdx.x * 2 + st) * 64;
        __syncthreads();
        {
            int row = tid >> 3, c0 = (tid & 7) * 8;
            size_t g = ((size_t)(b * Ll + l0 + row)) * 2048 + h * 64 + c0;
            u16x8 vh = *(const u16x8*)(QKh + g);
            *(u16x8*)&sQh[row * 72 + c0] = vh;
            float s = 0.f;
            if (NM == 3) {
                u16x8 vl = *(const u16x8*)(QKl + g);
                *(u16x8*)&sQl[row * 72 + c0] = vl;
#pragma unroll
                for (int j = 0; j < 8; j++) { float a = bf2f(vh[j]) + bf2f(vl[j]); s += a * a; }
            } else {
#pragma unroll
                for (int j = 0; j < 8; j++) { float a = bf2f(vh[j]); s += a * a; }
            }
            s += __shfl_xor(s, 1); s += __shfl_xor(s, 2); s += __shfl_xor(s, 4);
            if ((tid & 7) == 0) snsq[row] = s * 0.0625f;
        }
        __syncthreads();
#pragma unroll
        for (int fm = 0; fm < 2; fm++) {
            f32x4 ap[4];
#pragma unroll
            for (int fn = 0; fn < 4; fn++)
#pragma unroll
                for (int r = 0; r < 4; r++) ap[fn][r] = 0.f;
#pragma unroll
            for (int ks = 0; ks < 2; ks++) {
                s16x8 aH = *(const s16x8*)&sQh[(lh * 32 + fm * 16 + lr) * 72 + ks * 32 + lk];
                s16x8 aL;
                if (NM == 3) aL = *(const s16x8*)&sQl[(lh * 32 + fm * 16 + lr) * 72 + ks * 32 + lk];
#pragma unroll
                for (int fn = 0; fn < 4; fn++) {
                    ap[fn] = mfma16(aH, wbh[fn][ks], ap[fn]);
                    ap[fn] = mfma16(aH, wbl[fn][ks], ap[fn]);
                    if (NM == 3) ap[fn] = mfma16(aL, wbh[fn][ks], ap[fn]);
                }
            }
#pragma unroll
            for (int fn = 0; fn < 4; fn++)
#pragma unroll
                for (int r = 0; r < 4; r++) {
                    int l = lh * 32 + fm * 16 + (lane >> 4) * 4 + r;
                    int m = mq * 64 + fn * 16 + lr;
                    sQf[l * 264 + m] = f2bf(__expf(ap[fn][r] - snsq[l]) * 0.0625f);
                }
        }
        __syncthreads();
        {
            int l = tid >> 3, m0 = (tid & 7) * 32;
            float s = 0.f;
#pragma unroll
            for (int j = 0; j < 32; j++) s += bf2f(sQf[l * 264 + m0 + j]) * sKs[m0 + j];
            s += __shfl_xor(s, 1); s += __shfl_xor(s, 2); s += __shfl_xor(s, 4);
            if ((tid & 7) == 0) snorm[l] = s;
        }
        f32x4 aa[2];
#pragma unroll
        for (int fn = 0; fn < 2; fn++)
#pragma unroll
            for (int r = 0; r < 4; r++) aa[fn][r] = 0.f;
#pragma unroll
        for (int ks = 0; ks < 8; ks++) {
            s16x8 a = *(const s16x8*)&sQf[(af * 16 + lr) * 264 + ks * 32 + lk];
            aa[0] = mfma16(a, kvb[0][ks], aa[0]);
            aa[1] = mfma16(a, kvb[1][ks], aa[1]);
        }
        __syncthreads();
        float* ep = (float*)sQf; // [64][68]
#pragma unroll
        for (int fn = 0; fn < 2; fn++)
#pragma unroll
            for (int r = 0; r < 4; r++) {
                int l = af * 16 + (lane >> 4) * 4 + r;
                int d = ad * 32 + fn * 16 + lr;
                ep[l * 68 + d] = aa[fn][r];
            }
        __syncthreads();
        {
            int l = tid >> 3, d0 = (tid & 7) * 8;
            float inv = 1.0f / fmaxf(snorm[l], 1e-6f);
            u16x8 o;
#pragma unroll
            for (int j = 0; j < 8; j++) o[j] = f2bf(ep[l * 68 + d0 + j] * inv);
            *(u16x8*)(attn + ((size_t)(b * Ll + l0 + l)) * 1024 + h * 64 + d0) = o;
        }
    }
}

// ---------------- final GEMM: attn @ Wo^T + bo -> f32 out (double-buffered) ----------------
__global__ __launch_bounds__(256) void k_gemm_out(const u16* __restrict__ Ab, const u16* __restrict__ Bw,
                                                  const float* __restrict__ bias, float* __restrict__ outp) {
    __shared__ __align__(16) u16 sm[16896]; // 2 buffers x 2 x [128][32] tiles; epilogue [32][132] f32 fits
    const int tid = threadIdx.x, wave = tid >> 6, lane = tid & 63;
    const int lr = lane & 15, lk = (lane >> 4) * 8;
    const int m0 = blockIdx.y * 128, n0 = blockIdx.x * 128;
    const int wm = (wave >> 1) * 64, wn = (wave & 1) * 64;
    constexpr int TILE = 4096, BUF = 8192;

    int aoff[4], boff[4];
#pragma unroll
    for (int f = 0; f < 4; f++) {
        int ra = wm + f * 16 + lr;
        aoff[f] = ra * 32 + (lk ^ (((ra >> 1) & 3) << 3));
        int rb = wn + f * 16 + lr;
        boff[f] = rb * 32 + (lk ^ (((rb >> 1) & 3) << 3));
    }

    f32x4 acc[4][4];
#pragma unroll
    for (int i = 0; i < 4; i++)
#pragma unroll
        for (int j = 0; j < 4; j++)
#pragma unroll
            for (int r = 0; r < 4; r++) acc[i][j][r] = 0.f;

    STAGE_T(sm, Ab, m0, 0)
    STAGE_T(sm + TILE, Bw, n0, 0)
    __syncthreads();

    int cur = 0;
    for (int k0 = 0; k0 < 1024; k0 += 32) {
        u16* buf  = sm + cur * BUF;
        u16* nbuf = sm + (cur ^ 1) * BUF;
        if (k0 + 32 < 1024) {
            STAGE_T(nbuf, Ab, m0, k0 + 32)
            STAGE_T(nbuf + TILE, Bw, n0, k0 + 32)
        }
        s16x8 a[4], bb[4];
#pragma unroll
        for (int f = 0; f < 4; f++) {
            a[f]  = *(const s16x8*)&buf[aoff[f]];
            bb[f] = *(const s16x8*)&buf[TILE + boff[f]];
        }
#pragma unroll
        for (int i = 0; i < 4; i++)
#pragma unroll
            for (int j = 0; j < 4; j++)
                acc[i][j] = mfma16(a[i], bb[j], acc[i][j]);
        __syncthreads();
        cur ^= 1;
    }
    float* ep = (float*)sm; // [32][132]
    for (int g = 0; g < 4; g++) {
        __syncthreads();
        if ((wave >> 1) == (g >> 1)) {
#pragma unroll
            for (int fi = 0; fi < 2; fi++) {
                int fm = (g & 1) * 2 + fi;
#pragma unroll
                for (int j = 0; j < 4; j++)
#pragma unroll
                    for (int r = 0; r < 4; r++)
                        ep[(fi * 16 + (lane >> 4) * 4 + r) * 132 + wn + j * 16 + lr] = acc[fm][j][r];
            }
        }
        __syncthreads();
        int row = tid >> 3, c0 = (tid & 7) * 16;
        int grow = m0 + g * 32 + row;
        float vv[16];
#pragma unroll
        for (int j = 0; j < 16; j++) vv[j] = ep[row * 132 + c0 + j] + bias[n0 + c0 + j];
#pragma unroll
        for (int p = 0; p < 4; p++) {
            f32x4 t;
#pragma unroll
            for (int q = 0; q < 4; q++) t[q] = vv[p * 4 + q];
            *(f32x4*)(outp + (size_t)grow * 1024 + n0 + c0 + p * 4) = t;
        }
    }
}

extern "C" void kernel_launch(void* const* d_in, const int* in_sizes, int n_in,
                              void* d_out, int out_size, void* d_ws, size_t ws_size,
                              hipStream_t stream) {
    (void)in_sizes; (void)n_in; (void)out_size;
    const float* x  = (const float*)d_in[0];
    const float* Wq = (const float*)d_in[1];
    const float* Wk = (const float*)d_in[2];
    const float* Wv = (const float*)d_in[3];
    const float* Wo = (const float*)d_in[4];
    const float* bo = (const float*)d_in[5];
    const float* om = (const float*)d_in[6];

    // Path A (split Q/K storage) needs 255,983,616 B; Path B needs 188,874,752 B.
    const bool pa = ws_size >= (size_t)255983616ull;

    char* w = (char*)d_ws;
    size_t o = 0;
    auto take = [&](size_t n) { char* p = w + o; o += n; return p; };
    u16* QKh = (u16*)take(67108864);
    u16* QKl = pa ? (u16*)take(67108864) : QKh; // alias in path B (never read)
    u16* Vb  = (u16*)take(33554432);
    u16* xh  = (u16*)take(33554432);
    u16* xl  = (u16*)take(33554432);
    u16* Wh  = (u16*)take(6291456);
    u16* Wl  = (u16*)take(6291456);
    u16* Wob = (u16*)take(2097152);
    u16* wth = (u16*)take(32768);
    u16* wtl = (u16*)take(32768);
    float* KVacc = (float*)take(4194304);
    float* Ksum  = (float*)take(65536);   // contiguous after KVacc for k_zero
    u16* KVt = (u16*)take(2097152);
    u16* attn = Vb; // alias: V dead after k_phik_kv

    k_split<<<16384, 256, 0, stream>>>(x, xh, xl);
    k_split<<<1024, 256, 0, stream>>>(Wq, Wh, Wl);
    k_split<<<1024, 256, 0, stream>>>(Wk, Wh + 1048576, Wl + 1048576);
    k_split<<<1024, 256, 0, stream>>>(Wv, Wh + 2097152, Wl + 2097152);
    k_conv<<<1024, 256, 0, stream>>>(Wo, Wob);
    k_omega<<<64, 256, 0, stream>>>(om, wth, wtl);
    k_zero<<<1040, 256, 0, stream>>>(KVacc, 1064960); // KVacc + Ksum

    if (pa) k_gemm_qkv<true ><<<dim3(24, 128), 256, 0, stream>>>(xh, xl, Wh, Wl, QKh, QKl, Vb);
    else    k_gemm_qkv<false><<<dim3(24, 128), 256, 0, stream>>>(xh, xl, Wh, Wl, QKh, QKl, Vb);

    if (pa) k_phik_kv<3><<<dim3(8, 64), 256, 0, stream>>>(QKh, QKl, wth, wtl, Vb, KVacc, Ksum);
    else    k_phik_kv<2><<<dim3(8, 64), 256, 0, stream>>>(QKh, QKl, wth, wtl, Vb, KVacc, Ksum);

    k_kvt<<<4096, 256, 0, stream>>>(KVacc, KVt);

    if (pa) k_phiq_attn<3><<<dim3(32, 64), 512, 0, stream>>>(QKh, QKl, wth, wtl, KVt, Ksum, attn);
    else    k_phiq_attn<2><<<dim3(32, 64), 512, 0, stream>>>(QKh, QKl, wth, wtl, KVt, Ksum, attn);

    k_gemm_out<<<dim3(8, 128), 256, 0, stream>>>(attn, Wob, bo, (float*)d_out);
}

// Round 5
// 410.447 us; speedup vs baseline: 1.6545x; 1.3884x over previous
//
#include <hip/hip_runtime.h>

typedef unsigned short u16;
typedef __attribute__((ext_vector_type(4))) float f32x4;
typedef _Float16 f16x8 __attribute__((ext_vector_type(8)));
typedef __attribute__((ext_vector_type(4))) u16   u16x4;
typedef __attribute__((ext_vector_type(8))) u16   u16x8;

#define DEV static __device__ __forceinline__

constexpr int Ll = 4096;

DEV float h2f(u16 v) { _Float16 h; __builtin_memcpy(&h, &v, 2); return (float)h; }
DEV u16 f2h(float f) { _Float16 h = (_Float16)f; u16 u; __builtin_memcpy(&u, &h, 2); return u; }

DEV f32x4 mfma16h(f16x8 a, f16x8 b, f32x4 c) {
    return __builtin_amdgcn_mfma_f32_16x16x32_f16(a, b, c, 0, 0, 0);
}

#if defined(__has_builtin)
#if __has_builtin(__builtin_amdgcn_global_load_lds)
#define HAS_GLLDS 1
#endif
#endif
#ifndef HAS_GLLDS
#define HAS_GLLDS 0
#endif

// Stage a [128][32] u16 tile (8KB) into DST with XOR-swizzle col^(((row>>1)&3)<<3).
// gload_lds path: linear LDS dest (wave-uniform base + lane*16), inverse-swizzled
// global source (same involution). Fallback: reg-staged swizzled writes.
#if HAS_GLLDS
#define STAGE_T(DST, SRC, ROWBASE, KK)                                                    \
  { _Pragma("unroll") for (int j_ = 0; j_ < 2; j_++) {                                    \
      int row_ = wave * 32 + j_ * 16 + (lane >> 2);                                       \
      int col_ = ((lane & 3) ^ ((row_ >> 1) & 3)) * 8;                                    \
      const u16* gp_ = (SRC) + (size_t)((ROWBASE) + row_) * 1024 + (KK) + col_;           \
      __builtin_amdgcn_global_load_lds(                                                   \
          (const __attribute__((address_space(1))) unsigned int*)gp_,                     \
          (__attribute__((address_space(3))) unsigned int*)((DST) + (wave * 2 + j_) * 512), \
          16, 0, 0); } }
#else
#define STAGE_T(DST, SRC, ROWBASE, KK)                                                    \
  { int row_ = tid >> 1, cb_ = (tid & 1) * 16;                                            \
    const u16* gp_ = (SRC) + (size_t)((ROWBASE) + row_) * 1024 + (KK) + cb_;              \
    int g_ = ((row_ >> 1) & 3) << 3;                                                      \
    *(u16x8*)&(DST)[row_ * 32 + (cb_ ^ g_)]       = *(const u16x8*)gp_;                   \
    *(u16x8*)&(DST)[row_ * 32 + ((cb_ + 8) ^ g_)] = *(const u16x8*)(gp_ + 8); }
#endif

// ---------------- converts ----------------
__global__ __launch_bounds__(256) void k_half(const float* __restrict__ s, u16* __restrict__ d) {
    size_t i = ((size_t)blockIdx.x * 256 + threadIdx.x) * 4;
    f32x4 v = *(const f32x4*)(s + i);
    u16x4 h;
#pragma unroll
    for (int j = 0; j < 4; j++) h[j] = f2h(v[j]);
    *(u16x4*)(d + i) = h;
}

// wt[m*64+d] = omega[d*256+m] * DH^-0.25 (fp16)
__global__ __launch_bounds__(256) void k_omega(const float* __restrict__ om, u16* __restrict__ wh) {
    int i = blockIdx.x * 256 + threadIdx.x; // 16384
    int m = i >> 6, d = i & 63;
    wh[i] = f2h(om[d * 256 + m] * 0.35355339059327373f);
}

__global__ __launch_bounds__(256) void k_zero(float* __restrict__ p, int n) {
    int i = (blockIdx.x * 256 + threadIdx.x) * 4;
    if (i < n) { f32x4 z; z[0]=0.f; z[1]=0.f; z[2]=0.f; z[3]=0.f; *(f32x4*)(p + i) = z; }
}

// ---------------- QKV GEMM: fp16 single-MFMA, swizzled LDS, gload_lds, double-buffered ----------------
// Output: Q,K (n0<2048) -> QK[row][2048] fp16 ; V (n0>=2048) -> Vb fp16.
__global__ __launch_bounds__(256) void k_gemm_qkv(
    const u16* __restrict__ Ax, const u16* __restrict__ Bw,
    u16* __restrict__ QK, u16* __restrict__ Vb) {
    __shared__ __align__(16) u16 sm[16384]; // 32 KB: 2 bufs x 2 x [128][32] tiles; epilogue fits
    const int tid = threadIdx.x, wave = tid >> 6, lane = tid & 63;
    const int lr = lane & 15, lk = (lane >> 4) * 8;
    const int m0 = blockIdx.y * 128, n0 = blockIdx.x * 128;
    const int wm = (wave >> 1) * 64, wn = (wave & 1) * 64;
    const int sec = n0 >> 10;
    constexpr int TILE = 4096, BUF = 8192;

    int aoff[4], boff[4];
#pragma unroll
    for (int f = 0; f < 4; f++) {
        int ra = wm + f * 16 + lr;
        aoff[f] = ra * 32 + (lk ^ (((ra >> 1) & 3) << 3));
        int rb = wn + f * 16 + lr;
        boff[f] = rb * 32 + (lk ^ (((rb >> 1) & 3) << 3));
    }

    f32x4 acc[4][4];
#pragma unroll
    for (int i = 0; i < 4; i++)
#pragma unroll
        for (int j = 0; j < 4; j++)
#pragma unroll
            for (int r = 0; r < 4; r++) acc[i][j][r] = 0.f;

    STAGE_T(sm, Ax, m0, 0)
    STAGE_T(sm + TILE, Bw, n0, 0)
    __syncthreads();

    int cur = 0;
    for (int k0 = 0; k0 < 1024; k0 += 32) {
        u16* buf  = sm + cur * BUF;
        u16* nbuf = sm + (cur ^ 1) * BUF;
        if (k0 + 32 < 1024) { // issue next tile's loads BEFORE computing current
            STAGE_T(nbuf, Ax, m0, k0 + 32)
            STAGE_T(nbuf + TILE, Bw, n0, k0 + 32)
        }
        f16x8 a[4], bb[4];
#pragma unroll
        for (int f = 0; f < 4; f++) {
            a[f]  = *(const f16x8*)&buf[aoff[f]];
            bb[f] = *(const f16x8*)&buf[TILE + boff[f]];
        }
#pragma unroll
        for (int i = 0; i < 4; i++)
#pragma unroll
            for (int j = 0; j < 4; j++)
                acc[i][j] = mfma16h(a[i], bb[j], acc[i][j]);
        __syncthreads();
        cur ^= 1;
    }

    // epilogue: restage 32-row groups through LDS for coalesced fp16 stores
    float* ep = (float*)sm; // [32][132] f32 = 16896 B
    for (int g = 0; g < 4; g++) {
        __syncthreads();
        if ((wave >> 1) == (g >> 1)) {
#pragma unroll
            for (int fi = 0; fi < 2; fi++) {
                int fm = (g & 1) * 2 + fi;
#pragma unroll
                for (int j = 0; j < 4; j++)
#pragma unroll
                    for (int r = 0; r < 4; r++)
                        ep[(fi * 16 + (lane >> 4) * 4 + r) * 132 + wn + j * 16 + lr] = acc[fm][j][r];
            }
        }
        __syncthreads();
        int row = tid >> 3, c0 = (tid & 7) * 16;
        int grow = m0 + g * 32 + row;
        u16x8 h0, h1;
#pragma unroll
        for (int j = 0; j < 8; j++) {
            h0[j] = f2h(ep[row * 132 + c0 + j]);
            h1[j] = f2h(ep[row * 132 + c0 + 8 + j]);
        }
        if (sec < 2) {
            size_t o = (size_t)grow * 2048 + (n0 + c0);
            *(u16x8*)(QK + o) = h0; *(u16x8*)(QK + o + 8) = h1;
        } else {
            size_t o = (size_t)grow * 1024 + (n0 - 2048 + c0);
            *(u16x8*)(Vb + o) = h0; *(u16x8*)(Vb + o + 8) = h1;
        }
    }
}

// ---------------- fused phi(K) + KV + Ksum (fp16; phi(K) scaled by extra 1/16) ----------------
__global__ __launch_bounds__(256) void k_phik_kv(
    const u16* __restrict__ QK, const u16* __restrict__ wt,
    const u16* __restrict__ Vb, float* __restrict__ KVacc, float* __restrict__ Ksum) {
    __shared__ __align__(16) u16 sKh[64 * 72];
    __shared__ __align__(16) u16 sVt[64 * 72];
    __shared__ __align__(16) u16 sKfT[256 * 72];
    __shared__ float snsq[64];
    const int tid = threadIdx.x, wave = tid >> 6, lane = tid & 63;
    const int lr = lane & 15, lk = (lane >> 4) * 8;
    const int kc = blockIdx.x, bh = blockIdx.y;
    const int b = bh >> 4, h = bh & 15;

    f16x8 wb[4][2];
#pragma unroll
    for (int fn = 0; fn < 4; fn++)
#pragma unroll
        for (int ks = 0; ks < 2; ks++)
            wb[fn][ks] = *(const f16x8*)(wt + (size_t)(wave * 64 + fn * 16 + lr) * 64 + ks * 32 + lk);

    f32x4 akv[4][4];
#pragma unroll
    for (int i = 0; i < 4; i++)
#pragma unroll
        for (int j = 0; j < 4; j++)
#pragma unroll
            for (int r = 0; r < 4; r++) akv[i][j][r] = 0.f;
    float ksm[4] = {0.f, 0.f, 0.f, 0.f};

    for (int it = 0; it < 8; it++) {
        int l0 = kc * 512 + it * 64;
        __syncthreads();
        { // stage K + nsq
            int row = tid >> 2, c0 = (tid & 3) * 16;
            size_t g = ((size_t)(b * Ll + l0 + row)) * 2048 + 1024 + h * 64 + c0;
            u16x8 h0 = *(const u16x8*)(QK + g);
            u16x8 h1 = *(const u16x8*)(QK + g + 8);
            *(u16x8*)&sKh[row * 72 + c0]     = h0;
            *(u16x8*)&sKh[row * 72 + c0 + 8] = h1;
            float s = 0.f;
#pragma unroll
            for (int j = 0; j < 8; j++) {
                float a = h2f(h0[j]); s += a * a;
                float c = h2f(h1[j]); s += c * c;
            }
            s += __shfl_xor(s, 1); s += __shfl_xor(s, 2);
            if ((tid & 3) == 0) snsq[row] = s * 0.0625f;
        }
        { // stage V transposed
            int l = tid >> 2, d0 = (tid & 3) * 16;
            size_t g = ((size_t)(b * Ll + l0 + l)) * 1024 + h * 64 + d0;
            u16x8 v0 = *(const u16x8*)(Vb + g);
            u16x8 v1 = *(const u16x8*)(Vb + g + 8);
#pragma unroll
            for (int j = 0; j < 8; j++) {
                sVt[(d0 + j) * 72 + l] = v0[j];
                sVt[(d0 + 8 + j) * 72 + l] = v1[j];
            }
        }
        __syncthreads();
#pragma unroll
        for (int fm = 0; fm < 4; fm++) {
            f32x4 ap[4];
#pragma unroll
            for (int fn = 0; fn < 4; fn++)
#pragma unroll
                for (int r = 0; r < 4; r++) ap[fn][r] = 0.f;
#pragma unroll
            for (int ks = 0; ks < 2; ks++) {
                f16x8 aH = *(const f16x8*)&sKh[(fm * 16 + lr) * 72 + ks * 32 + lk];
#pragma unroll
                for (int fn = 0; fn < 4; fn++)
                    ap[fn] = mfma16h(aH, wb[fn][ks], ap[fn]);
            }
#pragma unroll
            for (int fn = 0; fn < 4; fn++) {
                u16x4 pk;
#pragma unroll
                for (int r = 0; r < 4; r++) {
                    float ns = snsq[fm * 16 + (lane >> 4) * 4 + r];
                    float val = __expf(ap[fn][r] - ns) * 0.00390625f; // 1/256 (extra 1/16 folded)
                    ksm[fn] += val;
                    pk[r] = f2h(val);
                }
                *(u16x4*)&sKfT[(wave * 64 + fn * 16 + lr) * 72 + fm * 16 + (lane >> 4) * 4] = pk;
            }
        }
#pragma unroll
        for (int ks = 0; ks < 2; ks++) {
            f16x8 a4[4], b4[4];
#pragma unroll
            for (int f = 0; f < 4; f++) {
                a4[f] = *(const f16x8*)&sKfT[(wave * 64 + f * 16 + lr) * 72 + ks * 32 + lk];
                b4[f] = *(const f16x8*)&sVt[(f * 16 + lr) * 72 + ks * 32 + lk];
            }
#pragma unroll
            for (int fm = 0; fm < 4; fm++)
#pragma unroll
                for (int fn = 0; fn < 4; fn++)
                    akv[fm][fn] = mfma16h(a4[fm], b4[fn], akv[fm][fn]);
        }
    }
#pragma unroll
    for (int fm = 0; fm < 4; fm++)
#pragma unroll
        for (int fn = 0; fn < 4; fn++)
#pragma unroll
            for (int r = 0; r < 4; r++) {
                int m = wave * 64 + fm * 16 + (lane >> 4) * 4 + r;
                int d = fn * 16 + lr;
                atomicAdd(&KVacc[((size_t)bh << 14) + m * 64 + d], akv[fm][fn][r]);
            }
#pragma unroll
    for (int fn = 0; fn < 4; fn++) {
        ksm[fn] += __shfl_xor(ksm[fn], 16);
        ksm[fn] += __shfl_xor(ksm[fn], 32);
    }
    if (lane < 16) {
#pragma unroll
        for (int fn = 0; fn < 4; fn++)
            atomicAdd(&Ksum[bh * 256 + wave * 64 + fn * 16 + lane], ksm[fn]);
    }
}

// KVt[bh][d][m] = fp16(KVacc[bh][m][d])
__global__ __launch_bounds__(256) void k_kvt(const float* __restrict__ KVacc, u16* __restrict__ KVt) {
    int i = blockIdx.x * 256 + threadIdx.x;
    int bh = i >> 14, dd = (i >> 8) & 63, m = i & 255;
    KVt[i] = f2h(KVacc[((size_t)bh << 14) + m * 64 + dd]);
}

// ---------------- fused phi(Q) + norm + attn (fp16) ----------------
__global__ __launch_bounds__(512) void k_phiq_attn(
    const u16* __restrict__ QK, const u16* __restrict__ wt,
    const u16* __restrict__ KVt, const float* __restrict__ Ksum,
    u16* __restrict__ attn) {
    __shared__ __align__(16) u16 sQh[64 * 72];
    __shared__ __align__(16) u16 sQf[64 * 264];
    __shared__ float sKs[256];
    __shared__ float snsq[64];
    __shared__ float snorm[64];
    const int tid = threadIdx.x, wave = tid >> 6, lane = tid & 63;
    const int lr = lane & 15, lk = (lane >> 4) * 8;
    const int bh = blockIdx.y, b = bh >> 4, h = bh & 15;
    const int mq = wave & 3;
    const int lh = wave >> 2;
    const int af = wave & 3;
    const int ad = wave >> 2;

    f16x8 wb[4][2];
#pragma unroll
    for (int fn = 0; fn < 4; fn++)
#pragma unroll
        for (int ks = 0; ks < 2; ks++)
            wb[fn][ks] = *(const f16x8*)(wt + (size_t)(mq * 64 + fn * 16 + lr) * 64 + ks * 32 + lk);
    f16x8 kvb[2][8];
#pragma unroll
    for (int fn = 0; fn < 2; fn++)
#pragma unroll
        for (int ks = 0; ks < 8; ks++)
            kvb[fn][ks] = *(const f16x8*)(KVt + ((size_t)bh << 14) +
                                          (size_t)(ad * 32 + fn * 16 + lr) * 256 + ks * 32 + lk);
    if (tid < 256) sKs[tid] = Ksum[bh * 256 + tid];

    for (int st = 0; st < 2; st++) {
        const int l0 = (blockIdx.x * 2 + st) * 64;
        __syncthreads();
        {
            int row = tid >> 3, c0 = (tid & 7) * 8;
            size_t g = ((size_t)(b * Ll + l0 + row)) * 2048 + h * 64 + c0;
            u16x8 vh = *(const u16x8*)(QK + g);
            *(u16x8*)&sQh[row * 72 + c0] = vh;
            float s = 0.f;
#pragma unroll
            for (int j = 0; j < 8; j++) { float a = h2f(vh[j]); s += a * a; }
            s += __shfl_xor(s, 1); s += __shfl_xor(s, 2); s += __shfl_xor(s, 4);
            if ((tid & 7) == 0) snsq[row] = s * 0.0625f;
        }
        __syncthreads();
#pragma unroll
        for (int fm = 0; fm < 2; fm++) {
            f32x4 ap[4];
#pragma unroll
            for (int fn = 0; fn < 4; fn++)
#pragma unroll
                for (int r = 0; r < 4; r++) ap[fn][r] = 0.f;
#pragma unroll
            for (int ks = 0; ks < 2; ks++) {
                f16x8 aH = *(const f16x8*)&sQh[(lh * 32 + fm * 16 + lr) * 72 + ks * 32 + lk];
#pragma unroll
                for (int fn = 0; fn < 4; fn++)
                    ap[fn] = mfma16h(aH, wb[fn][ks], ap[fn]);
            }
#pragma unroll
            for (int fn = 0; fn < 4; fn++)
#pragma unroll
                for (int r = 0; r < 4; r++) {
                    int l = lh * 32 + fm * 16 + (lane >> 4) * 4 + r;
                    int m = mq * 64 + fn * 16 + lr;
                    sQf[l * 264 + m] = f2h(__expf(ap[fn][r] - snsq[l]) * 0.0625f);
                }
        }
        __syncthreads();
        {
            int l = tid >> 3, m0 = (tid & 7) * 32;
            float s = 0.f;
#pragma unroll
            for (int j = 0; j < 32; j++) s += h2f(sQf[l * 264 + m0 + j]) * sKs[m0 + j];
            s += __shfl_xor(s, 1); s += __shfl_xor(s, 2); s += __shfl_xor(s, 4);
            if ((tid & 7) == 0) snorm[l] = s;
        }
        f32x4 aa[2];
#pragma unroll
        for (int fn = 0; fn < 2; fn++)
#pragma unroll
            for (int r = 0; r < 4; r++) aa[fn][r] = 0.f;
#pragma unroll
        for (int ks = 0; ks < 8; ks++) {
            f16x8 a = *(const f16x8*)&sQf[(af * 16 + lr) * 264 + ks * 32 + lk];
            aa[0] = mfma16h(a, kvb[0][ks], aa[0]);
            aa[1] = mfma16h(a, kvb[1][ks], aa[1]);
        }
        __syncthreads();
        float* ep = (float*)sQf; // [64][68]
#pragma unroll
        for (int fn = 0; fn < 2; fn++)
#pragma unroll
            for (int r = 0; r < 4; r++) {
                int l = af * 16 + (lane >> 4) * 4 + r;
                int d = ad * 32 + fn * 16 + lr;
                ep[l * 68 + d] = aa[fn][r];
            }
        __syncthreads();
        {
            int l = tid >> 3, d0 = (tid & 7) * 8;
            // norm carries 1/16 from phi(K) extra scale: clamp = 1e-6/16
            float inv = 1.0f / fmaxf(snorm[l], 6.25e-8f);
            u16x8 o;
#pragma unroll
            for (int j = 0; j < 8; j++) o[j] = f2h(ep[l * 68 + d0 + j] * inv);
            *(u16x8*)(attn + ((size_t)(b * Ll + l0 + l)) * 1024 + h * 64 + d0) = o;
        }
    }
}

// ---------------- final GEMM: attn @ Wo^T + bo -> f32 out (fp16, double-buffered) ----------------
__global__ __launch_bounds__(256) void k_gemm_out(const u16* __restrict__ Ab, const u16* __restrict__ Bw,
                                                  const float* __restrict__ bias, float* __restrict__ outp) {
    __shared__ __align__(16) u16 sm[16896];
    const int tid = threadIdx.x, wave = tid >> 6, lane = tid & 63;
    const int lr = lane & 15, lk = (lane >> 4) * 8;
    const int m0 = blockIdx.y * 128, n0 = blockIdx.x * 128;
    const int wm = (wave >> 1) * 64, wn = (wave & 1) * 64;
    constexpr int TILE = 4096, BUF = 8192;

    int aoff[4], boff[4];
#pragma unroll
    for (int f = 0; f < 4; f++) {
        int ra = wm + f * 16 + lr;
        aoff[f] = ra * 32 + (lk ^ (((ra >> 1) & 3) << 3));
        int rb = wn + f * 16 + lr;
        boff[f] = rb * 32 + (lk ^ (((rb >> 1) & 3) << 3));
    }

    f32x4 acc[4][4];
#pragma unroll
    for (int i = 0; i < 4; i++)
#pragma unroll
        for (int j = 0; j < 4; j++)
#pragma unroll
            for (int r = 0; r < 4; r++) acc[i][j][r] = 0.f;

    STAGE_T(sm, Ab, m0, 0)
    STAGE_T(sm + TILE, Bw, n0, 0)
    __syncthreads();

    int cur = 0;
    for (int k0 = 0; k0 < 1024; k0 += 32) {
        u16* buf  = sm + cur * BUF;
        u16* nbuf = sm + (cur ^ 1) * BUF;
        if (k0 + 32 < 1024) {
            STAGE_T(nbuf, Ab, m0, k0 + 32)
            STAGE_T(nbuf + TILE, Bw, n0, k0 + 32)
        }
        f16x8 a[4], bb[4];
#pragma unroll
        for (int f = 0; f < 4; f++) {
            a[f]  = *(const f16x8*)&buf[aoff[f]];
            bb[f] = *(const f16x8*)&buf[TILE + boff[f]];
        }
#pragma unroll
        for (int i = 0; i < 4; i++)
#pragma unroll
            for (int j = 0; j < 4; j++)
                acc[i][j] = mfma16h(a[i], bb[j], acc[i][j]);
        __syncthreads();
        cur ^= 1;
    }
    float* ep = (float*)sm; // [32][132]
    for (int g = 0; g < 4; g++) {
        __syncthreads();
        if ((wave >> 1) == (g >> 1)) {
#pragma unroll
            for (int fi = 0; fi < 2; fi++) {
                int fm = (g & 1) * 2 + fi;
#pragma unroll
                for (int j = 0; j < 4; j++)
#pragma unroll
                    for (int r = 0; r < 4; r++)
                        ep[(fi * 16 + (lane >> 4) * 4 + r) * 132 + wn + j * 16 + lr] = acc[fm][j][r];
            }
        }
        __syncthreads();
        int row = tid >> 3, c0 = (tid & 7) * 16;
        int grow = m0 + g * 32 + row;
        float vv[16];
#pragma unroll
        for (int j = 0; j < 16; j++) vv[j] = ep[row * 132 + c0 + j] + bias[n0 + c0 + j];
#pragma unroll
        for (int p = 0; p < 4; p++) {
            f32x4 t;
#pragma unroll
            for (int q = 0; q < 4; q++) t[q] = vv[p * 4 + q];
            *(f32x4*)(outp + (size_t)grow * 1024 + n0 + c0 + p * 4) = t;
        }
    }
}

extern "C" void kernel_launch(void* const* d_in, const int* in_sizes, int n_in,
                              void* d_out, int out_size, void* d_ws, size_t ws_size,
                              hipStream_t stream) {
    (void)in_sizes; (void)n_in; (void)out_size; (void)ws_size;
    const float* x  = (const float*)d_in[0];
    const float* Wq = (const float*)d_in[1];
    const float* Wk = (const float*)d_in[2];
    const float* Wv = (const float*)d_in[3];
    const float* Wo = (const float*)d_in[4];
    const float* bo = (const float*)d_in[5];
    const float* om = (const float*)d_in[6];

    char* w = (char*)d_ws;
    size_t o = 0;
    auto take = [&](size_t n) { char* p = w + o; o += n; return p; };
    u16* QK  = (u16*)take(67108864);   // [16384][2048] fp16: Q | K
    u16* Vb  = (u16*)take(33554432);   // [16384][1024] fp16
    u16* xh  = (u16*)take(33554432);   // x fp16
    u16* Wc  = (u16*)take(6291456);    // Wq|Wk|Wv fp16 [3072][1024]
    u16* Wof = (u16*)take(2097152);    // Wo fp16
    u16* wt  = (u16*)take(32768);      // omega^T scaled fp16 [256][64]
    float* KVacc = (float*)take(4194304);
    float* Ksum  = (float*)take(65536);  // contiguous after KVacc for k_zero
    u16* KVt = (u16*)take(2097152);
    u16* attn = Vb; // alias: V dead after k_phik_kv

    k_half<<<16384, 256, 0, stream>>>(x, xh);
    k_half<<<1024, 256, 0, stream>>>(Wq, Wc);
    k_half<<<1024, 256, 0, stream>>>(Wk, Wc + 1048576);
    k_half<<<1024, 256, 0, stream>>>(Wv, Wc + 2097152);
    k_half<<<1024, 256, 0, stream>>>(Wo, Wof);
    k_omega<<<64, 256, 0, stream>>>(om, wt);
    k_zero<<<1040, 256, 0, stream>>>(KVacc, 1064960); // KVacc + Ksum

    k_gemm_qkv<<<dim3(24, 128), 256, 0, stream>>>(xh, Wc, QK, Vb);
    k_phik_kv<<<dim3(8, 64), 256, 0, stream>>>(QK, wt, Vb, KVacc, Ksum);
    k_kvt<<<4096, 256, 0, stream>>>(KVacc, KVt);
    k_phiq_attn<<<dim3(32, 64), 512, 0, stream>>>(QK, wt, KVt, Ksum, attn);
    k_gemm_out<<<dim3(8, 128), 256, 0, stream>>>(attn, Wof, bo, (float*)d_out);
}